// Round 1
// baseline (237.929 us; speedup 1.0000x reference)
//
#include <hip/hip_runtime.h>
#include <hip/hip_bf16.h>
#include <stdint.h>

// qk = q@k^T ; attn = softmax(0.125*qk) in-place over qk ; out = attn @ qk_raw
// ws: [qk bf16 33.5MB][qkT bf16 33.5MB] = 67 MB.
// Round 4: BK=64 as two BK=32 sub-stages per barrier pair (halves the
// vmcnt(0)-drain count, the ~20% structural stall of the m97 K-loop).
// MFMA order is bit-identical to round 3 -> absmax must stay 1.3125.

#define SS 2048
#define DD 512
#define BATCH 4

typedef __attribute__((ext_vector_type(8))) short short8;
typedef __attribute__((ext_vector_type(8))) _Float16 half8;
typedef __attribute__((ext_vector_type(4))) float floatx4;
typedef __attribute__((ext_vector_type(4))) float float4v;
typedef __attribute__((ext_vector_type(4))) unsigned int uintx4;

#define GLOBAL_AS const __attribute__((address_space(1)))
#define LDS_AS __attribute__((address_space(3)))

__device__ __forceinline__ float bf2f(uint32_t hbits) {
    union { uint32_t u; float f; } c; c.u = hbits << 16; return c.f;
}
__device__ __forceinline__ uint32_t f2bf_rne(float f) {
    union { float f; uint32_t u; } c; c.f = f;
    return (c.u + 0x7fffu + ((c.u >> 16) & 1u)) >> 16;
}
__device__ __forceinline__ uint32_t pk2h(float x, float y) {
    _Float16 hx = (_Float16)x, hy = (_Float16)y;   // RNE v_cvt_f16_f32
    union { _Float16 h; uint16_t u; } cx, cy;
    cx.h = hx; cy.h = hy;
    return (uint32_t)cx.u | ((uint32_t)cy.u << 16);
}

union PackU { uint32_t u[4]; short8 s8; };

// ---------------------------------------------------------------- GEMM1
// qk[s][t] = sum_d q[s][d]*k[t][d]  via single-pass fp16 MFMA, BK=64.
// writes qk (row-major bf16) and qkT (transposed bf16)
__global__ __launch_bounds__(256, 2) void gemm1_kernel(
    const float* __restrict__ Q, const float* __restrict__ K,
    uint16_t* __restrict__ qk, uint16_t* __restrict__ qkT)
{
    const int b  = blockIdx.z;
    const int s0 = blockIdx.y * 128;
    const int t0 = blockIdx.x * 128;
    const float* qb = Q + (size_t)b * SS * DD;
    const float* kb = K + (size_t)b * SS * DD;

    __shared__ uint16_t Ah[2 * 128 * 32];   // two BK=32 sub-tiles
    __shared__ uint16_t Bh[2 * 128 * 32];

    const int tid  = threadIdx.x;
    const int lane = tid & 63;
    const int wave = tid >> 6;
    const int wm   = wave >> 1;
    const int wn   = wave & 1;
    const int fm   = lane & 15;
    const int quad = lane >> 4;

    floatx4 acc[4][4];
#pragma unroll
    for (int i = 0; i < 4; ++i)
#pragma unroll
        for (int j = 0; j < 4; ++j)
            acc[i][j] = (floatx4)0.0f;

    const int r  = tid >> 1;          // staging row 0..127
    const int c0 = (tid & 1) * 16;    // staging col chunk (fp32 elems)
    const float* gA = qb + (size_t)(s0 + r) * DD + c0;
    const float* gB = kb + (size_t)(t0 + r) * DD + c0;

    for (int k0 = 0; k0 < DD; k0 += 64) {
        uint32_t pa[2][8], pb[2][8];
#pragma unroll
        for (int ks = 0; ks < 2; ++ks) {
            float4v a4[4], b4[4];
#pragma unroll
            for (int l = 0; l < 4; ++l) {
                a4[l] = *(const float4v*)(gA + k0 + ks * 32 + l * 4);
                b4[l] = *(const float4v*)(gB + k0 + ks * 32 + l * 4);
            }
#pragma unroll
            for (int l = 0; l < 4; ++l) {
                pa[ks][2 * l]     = pk2h(a4[l][0], a4[l][1]);
                pa[ks][2 * l + 1] = pk2h(a4[l][2], a4[l][3]);
                pb[ks][2 * l]     = pk2h(b4[l][0], b4[l][1]);
                pb[ks][2 * l + 1] = pk2h(b4[l][2], b4[l][3]);
            }
        }
        __syncthreads();   // previous iteration's LDS reads complete
#pragma unroll
        for (int ks = 0; ks < 2; ++ks) {
            PackU p;
            p.u[0]=pa[ks][0]; p.u[1]=pa[ks][1]; p.u[2]=pa[ks][2]; p.u[3]=pa[ks][3];
            *(short8*)(&Ah[ks * 4096 + r * 32 + c0]) = p.s8;
            p.u[0]=pa[ks][4]; p.u[1]=pa[ks][5]; p.u[2]=pa[ks][6]; p.u[3]=pa[ks][7];
            *(short8*)(&Ah[ks * 4096 + r * 32 + c0 + 8]) = p.s8;
            p.u[0]=pb[ks][0]; p.u[1]=pb[ks][1]; p.u[2]=pb[ks][2]; p.u[3]=pb[ks][3];
            *(short8*)(&Bh[ks * 4096 + r * 32 + c0]) = p.s8;
            p.u[0]=pb[ks][4]; p.u[1]=pb[ks][5]; p.u[2]=pb[ks][6]; p.u[3]=pb[ks][7];
            *(short8*)(&Bh[ks * 4096 + r * 32 + c0 + 8]) = p.s8;
        }
        __syncthreads();

#pragma unroll
        for (int ks = 0; ks < 2; ++ks) {
            half8 fa[4], fb[4];
#pragma unroll
            for (int mt = 0; mt < 4; ++mt)
                fa[mt] = *(const half8*)(&Ah[ks * 4096 + (wm * 64 + mt * 16 + fm) * 32 + quad * 8]);
#pragma unroll
            for (int nt = 0; nt < 4; ++nt)
                fb[nt] = *(const half8*)(&Bh[ks * 4096 + (wn * 64 + nt * 16 + fm) * 32 + quad * 8]);
#pragma unroll
            for (int mt = 0; mt < 4; ++mt)
#pragma unroll
                for (int nt = 0; nt < 4; ++nt)
                    acc[mt][nt] = __builtin_amdgcn_mfma_f32_16x16x32_f16(fa[mt], fb[nt], acc[mt][nt], 0, 0, 0);
        }
    }

    uint16_t* qkb  = qk  + (size_t)b * SS * SS;
    uint16_t* qkTb = qkT + (size_t)b * SS * SS;
#pragma unroll
    for (int mt = 0; mt < 4; ++mt) {
#pragma unroll
        for (int nt = 0; nt < 4; ++nt) {
            const int srow = s0 + wm * 64 + mt * 16 + quad * 4;
            const int tcol = t0 + wn * 64 + nt * 16 + fm;
            uint32_t b0 = f2bf_rne(acc[mt][nt][0]);
            uint32_t b1 = f2bf_rne(acc[mt][nt][1]);
            uint32_t b2 = f2bf_rne(acc[mt][nt][2]);
            uint32_t b3 = f2bf_rne(acc[mt][nt][3]);
            qkb[(size_t)(srow + 0) * SS + tcol] = (uint16_t)b0;
            qkb[(size_t)(srow + 1) * SS + tcol] = (uint16_t)b1;
            qkb[(size_t)(srow + 2) * SS + tcol] = (uint16_t)b2;
            qkb[(size_t)(srow + 3) * SS + tcol] = (uint16_t)b3;
            uint2 pk = make_uint2(b0 | (b1 << 16), b2 | (b3 << 16));
            *(uint2*)(&qkTb[(size_t)tcol * SS + srow]) = pk;
        }
    }
}

// ---------------------------------------------------------------- softmax
// in-place: qk row -> softmax(0.125*row), bf16. qkT keeps the raw values.
__global__ __launch_bounds__(256) void softmax_inplace(uint16_t* __restrict__ qk)
{
    const size_t row = blockIdx.x;
    uint16_t* x = qk + row * SS;
    const int tid  = threadIdx.x;
    const int lane = tid & 63;
    const int wave = tid >> 6;

    uintx4 raw = *(const uintx4*)(x + tid * 8);
    float v[8];
#pragma unroll
    for (int i = 0; i < 4; ++i) {
        uint32_t u = raw[i];
        v[2 * i]     = bf2f(u & 0xffffu) * 0.125f;
        v[2 * i + 1] = bf2f(u >> 16) * 0.125f;
    }
    float m = v[0];
#pragma unroll
    for (int j = 1; j < 8; ++j) m = fmaxf(m, v[j]);
#pragma unroll
    for (int off = 1; off < 64; off <<= 1) m = fmaxf(m, __shfl_xor(m, off, 64));
    __shared__ float red[8];
    if (lane == 0) red[wave] = m;
    __syncthreads();
    m = fmaxf(fmaxf(red[0], red[1]), fmaxf(red[2], red[3]));

    float s = 0.f;
#pragma unroll
    for (int j = 0; j < 8; ++j) { v[j] = __expf(v[j] - m); s += v[j]; }
#pragma unroll
    for (int off = 1; off < 64; off <<= 1) s += __shfl_xor(s, off, 64);
    if (lane == 0) red[4 + wave] = s;
    __syncthreads();
    s = (red[4] + red[5]) + (red[6] + red[7]);
    const float inv = 1.0f / s;
#pragma unroll
    for (int i = 0; i < 4; ++i)
        raw[i] = f2bf_rne(v[2 * i] * inv) | (f2bf_rne(v[2 * i + 1] * inv) << 16);
    *(uintx4*)(x + tid * 8) = raw;
}

// ---------------------------------------------------------------- GEMM2
// out[s][t] = sum_u attn[s][u] * qkT[t][u]
// m97 structure + supertile swizzle + BK=64 (two sub-stages, one barrier pair)
__global__ __launch_bounds__(256, 2) void gemm2_kernel(
    const uint16_t* __restrict__ attn, const uint16_t* __restrict__ qkT,
    float* __restrict__ out)
{
    const int b = blockIdx.z;
    // 4x4 supertile remap: 16 consecutive dispatch IDs cover a 4x4 tile square.
    const int lin = blockIdx.y * 16 + blockIdx.x;
    const int sup = lin >> 4;
    const int inn = lin & 15;
    const int ty_ = (sup >> 2) * 4 + ((inn >> 2) & 3);
    const int tx_ = (sup & 3) * 4 + (inn & 3);
    const int s0 = ty_ * 128;
    const int t0 = tx_ * 128;

    const uint16_t* ab = attn + (size_t)b * SS * SS;
    const uint16_t* bb = qkT  + (size_t)b * SS * SS;

    __shared__ uint16_t As[2 * 128 * 32];   // two BK=32 sub-tiles
    __shared__ uint16_t Bs[2 * 128 * 32];

    const int tid  = threadIdx.x;
    const int lane = tid & 63;
    const int wave = tid >> 6;
    const int wm = wave >> 1, wn = wave & 1;
    const int fm = lane & 15, quad = lane >> 4;

    floatx4 acc[4][4];
#pragma unroll
    for (int i = 0; i < 4; ++i)
#pragma unroll
        for (int j = 0; j < 4; ++j)
            acc[i][j] = (floatx4)0.0f;

    const int c0i = wave * 128 + lane;
    const int c1i = c0i + 64;
    const int rA0 = c0i >> 2, pA0 = c0i & 3;
    const int rA1 = c1i >> 2, pA1 = c1i & 3;
    const int ldsOff0 = (wave * 128) * 8;        // halfs
    const int ldsOff1 = (wave * 128 + 64) * 8;

    for (int k0 = 0; k0 < SS; k0 += 64) {
        __syncthreads();   // previous iteration's LDS reads complete
#pragma unroll
        for (int ks = 0; ks < 2; ++ks) {
            const int kc = k0 + ks * 32;
            uint16_t* asub = &As[ks * 4096];
            uint16_t* bsub = &Bs[ks * 4096];
            __builtin_amdgcn_global_load_lds(
                (GLOBAL_AS void*)(ab + (size_t)(s0 + rA0) * SS + kc + pA0 * 8),
                (LDS_AS void*)(asub + ldsOff0), 16, 0, 0);
            __builtin_amdgcn_global_load_lds(
                (GLOBAL_AS void*)(ab + (size_t)(s0 + rA1) * SS + kc + pA1 * 8),
                (LDS_AS void*)(asub + ldsOff1), 16, 0, 0);
            __builtin_amdgcn_global_load_lds(
                (GLOBAL_AS void*)(bb + (size_t)(t0 + rA0) * SS + kc + pA0 * 8),
                (LDS_AS void*)(bsub + ldsOff0), 16, 0, 0);
            __builtin_amdgcn_global_load_lds(
                (GLOBAL_AS void*)(bb + (size_t)(t0 + rA1) * SS + kc + pA1 * 8),
                (LDS_AS void*)(bsub + ldsOff1), 16, 0, 0);
        }
        __syncthreads();   // drains vmcnt -> data resident in LDS

#pragma unroll
        for (int ks = 0; ks < 2; ++ks) {
            short8 fa[4], fb[4];
#pragma unroll
            for (int mt = 0; mt < 4; ++mt)
                fa[mt] = *(const short8*)(&As[ks * 4096 + (wm * 64 + mt * 16 + fm) * 32 + quad * 8]);
#pragma unroll
            for (int nt = 0; nt < 4; ++nt)
                fb[nt] = *(const short8*)(&Bs[ks * 4096 + (wn * 64 + nt * 16 + fm) * 32 + quad * 8]);
#pragma unroll
            for (int mt = 0; mt < 4; ++mt)
#pragma unroll
                for (int nt = 0; nt < 4; ++nt)
                    acc[mt][nt] = __builtin_amdgcn_mfma_f32_16x16x32_bf16(fa[mt], fb[nt], acc[mt][nt], 0, 0, 0);
        }
    }

    float* ob = out + (size_t)b * SS * SS;
#pragma unroll
    for (int mt = 0; mt < 4; ++mt) {
#pragma unroll
        for (int nt = 0; nt < 4; ++nt) {
            const int srow = s0 + wm * 64 + mt * 16 + quad * 4;
            const int tcol = t0 + wn * 64 + nt * 16 + fm;
#pragma unroll
            for (int reg = 0; reg < 4; ++reg)
                ob[(size_t)(srow + reg) * SS + tcol] = acc[mt][nt][reg];
        }
    }
}

extern "C" void kernel_launch(void* const* d_in, const int* in_sizes, int n_in,
                              void* d_out, int out_size, void* d_ws, size_t ws_size,
                              hipStream_t stream) {
    const float* q = (const float*)d_in[0];
    const float* k = (const float*)d_in[1];
    float* out = (float*)d_out;

    uint16_t* qk  = (uint16_t*)d_ws;
    uint16_t* qkT = qk + (size_t)BATCH * SS * SS;

    dim3 grid(SS / 128, SS / 128, BATCH);
    gemm1_kernel<<<grid, 256, 0, stream>>>(q, k, qk, qkT);
    softmax_inplace<<<dim3(BATCH * SS), 256, 0, stream>>>(qk);
    gemm2_kernel<<<grid, 256, 0, stream>>>(qk, qkT, out);
}

// Round 2
// 228.682 us; speedup vs baseline: 1.0404x; 1.0404x over previous
//
#include <hip/hip_runtime.h>
#include <hip/hip_bf16.h>
#include <stdint.h>

// qk = q@k^T ; attn = softmax(0.125*qk) in-place over qk ; out = attn @ qk_raw
// ws: [qk bf16 33.5MB][qkT bf16 33.5MB] = 67 MB.
// Round 5: gemm2 rewritten as the 256^2 8-phase template (T2 swizzle +
// T3/T4 counted vmcnt + T5 setprio). gemm1/softmax unchanged.
// MFMA per-element accumulation order unchanged -> absmax must stay 1.3125.

#define SS 2048
#define DD 512
#define BATCH 4
#define NT 32   // K tiles of 64 in gemm2

typedef __attribute__((ext_vector_type(8))) short short8;
typedef __attribute__((ext_vector_type(8))) _Float16 half8;
typedef __attribute__((ext_vector_type(4))) float floatx4;
typedef __attribute__((ext_vector_type(4))) float float4v;
typedef __attribute__((ext_vector_type(4))) unsigned int uintx4;

#define GLOBAL_AS const __attribute__((address_space(1)))
#define LDS_AS __attribute__((address_space(3)))

__device__ __forceinline__ float bf2f(uint32_t hbits) {
    union { uint32_t u; float f; } c; c.u = hbits << 16; return c.f;
}
__device__ __forceinline__ uint32_t f2bf_rne(float f) {
    union { float f; uint32_t u; } c; c.f = f;
    return (c.u + 0x7fffu + ((c.u >> 16) & 1u)) >> 16;
}
__device__ __forceinline__ uint32_t pk2h(float x, float y) {
    _Float16 hx = (_Float16)x, hy = (_Float16)y;   // RNE v_cvt_f16_f32
    union { _Float16 h; uint16_t u; } cx, cy;
    cx.h = hx; cy.h = hy;
    return (uint32_t)cx.u | ((uint32_t)cy.u << 16);
}

union PackU { uint32_t u[4]; short8 s8; };

// ---------------------------------------------------------------- GEMM1
// qk[s][t] = sum_d q[s][d]*k[t][d]  via single-pass fp16 MFMA, BK=64.
// writes qk (row-major bf16) and qkT (transposed bf16)
__global__ __launch_bounds__(256, 2) void gemm1_kernel(
    const float* __restrict__ Q, const float* __restrict__ K,
    uint16_t* __restrict__ qk, uint16_t* __restrict__ qkT)
{
    const int b  = blockIdx.z;
    const int s0 = blockIdx.y * 128;
    const int t0 = blockIdx.x * 128;
    const float* qb = Q + (size_t)b * SS * DD;
    const float* kb = K + (size_t)b * SS * DD;

    __shared__ uint16_t Ah[2 * 128 * 32];   // two BK=32 sub-tiles
    __shared__ uint16_t Bh[2 * 128 * 32];

    const int tid  = threadIdx.x;
    const int lane = tid & 63;
    const int wave = tid >> 6;
    const int wm   = wave >> 1;
    const int wn   = wave & 1;
    const int fm   = lane & 15;
    const int quad = lane >> 4;

    floatx4 acc[4][4];
#pragma unroll
    for (int i = 0; i < 4; ++i)
#pragma unroll
        for (int j = 0; j < 4; ++j)
            acc[i][j] = (floatx4)0.0f;

    const int r  = tid >> 1;          // staging row 0..127
    const int c0 = (tid & 1) * 16;    // staging col chunk (fp32 elems)
    const float* gA = qb + (size_t)(s0 + r) * DD + c0;
    const float* gB = kb + (size_t)(t0 + r) * DD + c0;

    for (int k0 = 0; k0 < DD; k0 += 64) {
        uint32_t pa[2][8], pb[2][8];
#pragma unroll
        for (int ks = 0; ks < 2; ++ks) {
            float4v a4[4], b4[4];
#pragma unroll
            for (int l = 0; l < 4; ++l) {
                a4[l] = *(const float4v*)(gA + k0 + ks * 32 + l * 4);
                b4[l] = *(const float4v*)(gB + k0 + ks * 32 + l * 4);
            }
#pragma unroll
            for (int l = 0; l < 4; ++l) {
                pa[ks][2 * l]     = pk2h(a4[l][0], a4[l][1]);
                pa[ks][2 * l + 1] = pk2h(a4[l][2], a4[l][3]);
                pb[ks][2 * l]     = pk2h(b4[l][0], b4[l][1]);
                pb[ks][2 * l + 1] = pk2h(b4[l][2], b4[l][3]);
            }
        }
        __syncthreads();   // previous iteration's LDS reads complete
#pragma unroll
        for (int ks = 0; ks < 2; ++ks) {
            PackU p;
            p.u[0]=pa[ks][0]; p.u[1]=pa[ks][1]; p.u[2]=pa[ks][2]; p.u[3]=pa[ks][3];
            *(short8*)(&Ah[ks * 4096 + r * 32 + c0]) = p.s8;
            p.u[0]=pa[ks][4]; p.u[1]=pa[ks][5]; p.u[2]=pa[ks][6]; p.u[3]=pa[ks][7];
            *(short8*)(&Ah[ks * 4096 + r * 32 + c0 + 8]) = p.s8;
            p.u[0]=pb[ks][0]; p.u[1]=pb[ks][1]; p.u[2]=pb[ks][2]; p.u[3]=pb[ks][3];
            *(short8*)(&Bh[ks * 4096 + r * 32 + c0]) = p.s8;
            p.u[0]=pb[ks][4]; p.u[1]=pb[ks][5]; p.u[2]=pb[ks][6]; p.u[7==7?7:7]=pb[ks][7];
            p.u[0]=pb[ks][4]; p.u[1]=pb[ks][5]; p.u[2]=pb[ks][6]; p.u[3]=pb[ks][7];
            *(short8*)(&Bh[ks * 4096 + r * 32 + c0 + 8]) = p.s8;
        }
        __syncthreads();

#pragma unroll
        for (int ks = 0; ks < 2; ++ks) {
            half8 fa[4], fb[4];
#pragma unroll
            for (int mt = 0; mt < 4; ++mt)
                fa[mt] = *(const half8*)(&Ah[ks * 4096 + (wm * 64 + mt * 16 + fm) * 32 + quad * 8]);
#pragma unroll
            for (int nt = 0; nt < 4; ++nt)
                fb[nt] = *(const half8*)(&Bh[ks * 4096 + (wn * 64 + nt * 16 + fm) * 32 + quad * 8]);
#pragma unroll
            for (int mt = 0; mt < 4; ++mt)
#pragma unroll
                for (int nt = 0; nt < 4; ++nt)
                    acc[mt][nt] = __builtin_amdgcn_mfma_f32_16x16x32_f16(fa[mt], fb[nt], acc[mt][nt], 0, 0, 0);
        }
    }

    uint16_t* qkb  = qk  + (size_t)b * SS * SS;
    uint16_t* qkTb = qkT + (size_t)b * SS * SS;
#pragma unroll
    for (int mt = 0; mt < 4; ++mt) {
#pragma unroll
        for (int nt = 0; nt < 4; ++nt) {
            const int srow = s0 + wm * 64 + mt * 16 + quad * 4;
            const int tcol = t0 + wn * 64 + nt * 16 + fm;
            uint32_t b0 = f2bf_rne(acc[mt][nt][0]);
            uint32_t b1 = f2bf_rne(acc[mt][nt][1]);
            uint32_t b2 = f2bf_rne(acc[mt][nt][2]);
            uint32_t b3 = f2bf_rne(acc[mt][nt][3]);
            qkb[(size_t)(srow + 0) * SS + tcol] = (uint16_t)b0;
            qkb[(size_t)(srow + 1) * SS + tcol] = (uint16_t)b1;
            qkb[(size_t)(srow + 2) * SS + tcol] = (uint16_t)b2;
            qkb[(size_t)(srow + 3) * SS + tcol] = (uint16_t)b3;
            uint2 pk = make_uint2(b0 | (b1 << 16), b2 | (b3 << 16));
            *(uint2*)(&qkTb[(size_t)tcol * SS + srow]) = pk;
        }
    }
}

// ---------------------------------------------------------------- softmax
// in-place: qk row -> softmax(0.125*row), bf16. qkT keeps the raw values.
__global__ __launch_bounds__(256) void softmax_inplace(uint16_t* __restrict__ qk)
{
    const size_t row = blockIdx.x;
    uint16_t* x = qk + row * SS;
    const int tid  = threadIdx.x;
    const int lane = tid & 63;
    const int wave = tid >> 6;

    uintx4 raw = *(const uintx4*)(x + tid * 8);
    float v[8];
#pragma unroll
    for (int i = 0; i < 4; ++i) {
        uint32_t u = raw[i];
        v[2 * i]     = bf2f(u & 0xffffu) * 0.125f;
        v[2 * i + 1] = bf2f(u >> 16) * 0.125f;
    }
    float m = v[0];
#pragma unroll
    for (int j = 1; j < 8; ++j) m = fmaxf(m, v[j]);
#pragma unroll
    for (int off = 1; off < 64; off <<= 1) m = fmaxf(m, __shfl_xor(m, off, 64));
    __shared__ float red[8];
    if (lane == 0) red[wave] = m;
    __syncthreads();
    m = fmaxf(fmaxf(red[0], red[1]), fmaxf(red[2], red[3]));

    float s = 0.f;
#pragma unroll
    for (int j = 0; j < 8; ++j) { v[j] = __expf(v[j] - m); s += v[j]; }
#pragma unroll
    for (int off = 1; off < 64; off <<= 1) s += __shfl_xor(s, off, 64);
    if (lane == 0) red[4 + wave] = s;
    __syncthreads();
    s = (red[4] + red[5]) + (red[6] + red[7]);
    const float inv = 1.0f / s;
#pragma unroll
    for (int i = 0; i < 4; ++i)
        raw[i] = f2bf_rne(v[2 * i] * inv) | (f2bf_rne(v[2 * i + 1] * inv) << 16);
    *(uintx4*)(x + tid * 8) = raw;
}

// ---------------------------------------------------------------- GEMM2
// out[s][t] = sum_u attn[s][u] * qkT[t][u]
// 256^2 8-phase template: 512 thr / 8 waves (2Mx4N), per-wave 128x64 C,
// BK=64, LDS 128KB double-buffer, XOR slot swizzle (conflict-free ds_read_b128),
// counted vmcnt(4) once per K-tile, raw s_barrier pairs, setprio around MFMA.
// Staging schedule (hand-verified):
//   (t,p1): A(t+1) half0   [other buffer - always safe]
//   (t,p2): A(t+1) half1
//   (t,p3): B(t+2) half0   [same buffer as t; B reads of t end at P1 -> safe]
//   (t,p4): B(t+2) half1 ; vmcnt(4) ; barrier   [forces t+1 fully landed]
__global__ __launch_bounds__(512, 2) void gemm2_kernel(
    const uint16_t* __restrict__ attn, const uint16_t* __restrict__ qkT,
    float* __restrict__ out)
{
    const int b  = blockIdx.z;
    const int s0 = blockIdx.y * 256;
    const int t0 = blockIdx.x * 256;
    const uint16_t* ab = attn + (size_t)b * SS * SS;
    const uint16_t* bb = qkT  + (size_t)b * SS * SS;

    // A[2][256][64] bf16 @ u16-offset 0, B[2][256][64] @ 32768. 128 KiB total.
    __shared__ uint16_t smem[65536];

    const int tid  = threadIdx.x;
    const int lane = tid & 63;
    const int wave = tid >> 6;
    const int wm   = wave >> 2;   // 0..1  (M half)
    const int wn   = wave & 3;    // 0..3  (N quarter)
    const int fm   = lane & 15;
    const int quad = lane >> 4;

    floatx4 acc[8][4];
#pragma unroll
    for (int i = 0; i < 8; ++i)
#pragma unroll
        for (int j = 0; j < 4; ++j)
            acc[i][j] = (floatx4)0.0f;

    // ---- swizzled read addressing (u16 units within a [256][64] tile)
    // logical slot s = ks*4+quad ; physical slot = s ^ (row&7) ; row&7 == fm&7
    const int sl0  = (quad ^ (fm & 7)) * 8;          // ks=0 ; ks=1 -> sl0^32
    const int aoff = (wm * 128 + fm) * 64;           // + mt*1024 + slot
    const int boff = 32768 + (wn * 64 + fm) * 64;    // + nt*1024 + slot (+buf)

    // ---- staging decomposition: half-tile = 128 rows x 64 cols = 1024 x 16B
    // chunk c -> row c>>3, phys slot c&7 must hold logical slot (c&7)^(row&7)
    const int c0 = wave * 128 + lane;
    const int r0 = c0 >> 3;  const int l0 = ((c0 & 7) ^ (r0 & 7)) * 8;
    const int c1 = c0 + 64;
    const int r1 = c1 >> 3;  const int l1 = ((c1 & 7) ^ (r1 & 7)) * 8;
    const int ldsW = wave * 1024;   // wave-uniform LDS dest (u16), +512 issue1

    auto STAGE_A = [&](int tt, int h) {
        uint16_t* base = &smem[(tt & 1) * 16384 + h * 8192 + ldsW];
        __builtin_amdgcn_global_load_lds(
            (GLOBAL_AS void*)(ab + (size_t)(s0 + h * 128 + r0) * SS + tt * 64 + l0),
            (LDS_AS void*)(base), 16, 0, 0);
        __builtin_amdgcn_global_load_lds(
            (GLOBAL_AS void*)(ab + (size_t)(s0 + h * 128 + r1) * SS + tt * 64 + l1),
            (LDS_AS void*)(base + 512), 16, 0, 0);
    };
    auto STAGE_B = [&](int tt, int h) {
        uint16_t* base = &smem[32768 + (tt & 1) * 16384 + h * 8192 + ldsW];
        __builtin_amdgcn_global_load_lds(
            (GLOBAL_AS void*)(bb + (size_t)(t0 + h * 128 + r0) * SS + tt * 64 + l0),
            (LDS_AS void*)(base), 16, 0, 0);
        __builtin_amdgcn_global_load_lds(
            (GLOBAL_AS void*)(bb + (size_t)(t0 + h * 128 + r1) * SS + tt * 64 + l1),
            (LDS_AS void*)(base + 512), 16, 0, 0);
    };

    // ---- prologue: T0 fully + B(T1); allow B(T1)'s 4 loads in flight
    STAGE_A(0, 0); STAGE_A(0, 1); STAGE_B(0, 0); STAGE_B(0, 1);
    STAGE_B(1, 0); STAGE_B(1, 1);
    asm volatile("s_waitcnt vmcnt(4)" ::: "memory");
    __builtin_amdgcn_s_barrier();

    short8 aF[4], aF2[4], bF[4][2];

    for (int t = 0; t < NT; ++t) {
        const int abase = (t & 1) * 16384;   // A tile base (u16)
        const int bbase = (t & 1) * 16384;   // added to boff (B base folded in)

        // ===== P1: read B(all nt, both ks) + A(m0-3, ks0) ; stage A(t+1,h0)
#pragma unroll
        for (int nt = 0; nt < 4; ++nt) {
            bF[nt][0] = *(const short8*)&smem[bbase + boff + nt * 1024 + sl0];
            bF[nt][1] = *(const short8*)&smem[bbase + boff + nt * 1024 + (sl0 ^ 32)];
        }
#pragma unroll
        for (int m = 0; m < 4; ++m)
            aF[m] = *(const short8*)&smem[abase + aoff + m * 1024 + sl0];
        if (t + 1 < NT) STAGE_A(t + 1, 0);
        __builtin_amdgcn_s_barrier();
        asm volatile("s_waitcnt lgkmcnt(0)" ::: "memory");
        __builtin_amdgcn_s_setprio(1);
#pragma unroll
        for (int m = 0; m < 4; ++m)
#pragma unroll
            for (int nt = 0; nt < 4; ++nt)
                acc[m][nt] = __builtin_amdgcn_mfma_f32_16x16x32_bf16(aF[m], bF[nt][0], acc[m][nt], 0, 0, 0);
        __builtin_amdgcn_s_setprio(0);
        __builtin_amdgcn_s_barrier();

        // ===== P2: read A(m4-7, ks0) ; stage A(t+1,h1) ; mfma m4-7 ks0
#pragma unroll
        for (int m = 0; m < 4; ++m)
            aF2[m] = *(const short8*)&smem[abase + aoff + (m + 4) * 1024 + sl0];
        if (t + 1 < NT) STAGE_A(t + 1, 1);
        __builtin_amdgcn_s_barrier();
        asm volatile("s_waitcnt lgkmcnt(0)" ::: "memory");
        __builtin_amdgcn_s_setprio(1);
#pragma unroll
        for (int m = 0; m < 4; ++m)
#pragma unroll
            for (int nt = 0; nt < 4; ++nt)
                acc[m + 4][nt] = __builtin_amdgcn_mfma_f32_16x16x32_bf16(aF2[m], bF[nt][0], acc[m + 4][nt], 0, 0, 0);
        __builtin_amdgcn_s_setprio(0);
        __builtin_amdgcn_s_barrier();

        // ===== P3: read A(m0-3, ks1) ; stage B(t+2,h0) ; mfma m0-3 ks1
#pragma unroll
        for (int m = 0; m < 4; ++m)
            aF[m] = *(const short8*)&smem[abase + aoff + m * 1024 + (sl0 ^ 32)];
        if (t + 2 < NT) STAGE_B(t + 2, 0);
        __builtin_amdgcn_s_barrier();
        asm volatile("s_waitcnt lgkmcnt(0)" ::: "memory");
        __builtin_amdgcn_s_setprio(1);
#pragma unroll
        for (int m = 0; m < 4; ++m)
#pragma unroll
            for (int nt = 0; nt < 4; ++nt)
                acc[m][nt] = __builtin_amdgcn_mfma_f32_16x16x32_bf16(aF[m], bF[nt][1], acc[m][nt], 0, 0, 0);
        __builtin_amdgcn_s_setprio(0);
        __builtin_amdgcn_s_barrier();

        // ===== P4: read A(m4-7, ks1) ; stage B(t+2,h1) ; vmcnt ; mfma m4-7 ks1
#pragma unroll
        for (int m = 0; m < 4; ++m)
            aF2[m] = *(const short8*)&smem[abase + aoff + (m + 4) * 1024 + (sl0 ^ 32)];
        if (t + 2 < NT) {
            STAGE_B(t + 2, 1);
            asm volatile("s_waitcnt vmcnt(4)" ::: "memory");
        } else {
            asm volatile("s_waitcnt vmcnt(0)" ::: "memory");
        }
        __builtin_amdgcn_s_barrier();
        asm volatile("s_waitcnt lgkmcnt(0)" ::: "memory");
        __builtin_amdgcn_s_setprio(1);
#pragma unroll
        for (int m = 0; m < 4; ++m)
#pragma unroll
            for (int nt = 0; nt < 4; ++nt)
                acc[m + 4][nt] = __builtin_amdgcn_mfma_f32_16x16x32_bf16(aF2[m], bF[nt][1], acc[m + 4][nt], 0, 0, 0);
        __builtin_amdgcn_s_setprio(0);
        __builtin_amdgcn_s_barrier();
    }

    float* ob = out + (size_t)b * SS * SS;
#pragma unroll
    for (int mt = 0; mt < 8; ++mt) {
#pragma unroll
        for (int nt = 0; nt < 4; ++nt) {
            const int srow = s0 + wm * 128 + mt * 16 + quad * 4;
            const int tcol = t0 + wn * 64 + nt * 16 + fm;
#pragma unroll
            for (int reg = 0; reg < 4; ++reg)
                ob[(size_t)(srow + reg) * SS + tcol] = acc[mt][nt][reg];
        }
    }
}

extern "C" void kernel_launch(void* const* d_in, const int* in_sizes, int n_in,
                              void* d_out, int out_size, void* d_ws, size_t ws_size,
                              hipStream_t stream) {
    const float* q = (const float*)d_in[0];
    const float* k = (const float*)d_in[1];
    float* out = (float*)d_out;

    uint16_t* qk  = (uint16_t*)d_ws;
    uint16_t* qkT = qk + (size_t)BATCH * SS * SS;

    dim3 grid1(SS / 128, SS / 128, BATCH);
    gemm1_kernel<<<grid1, 256, 0, stream>>>(q, k, qk, qkT);
    softmax_inplace<<<dim3(BATCH * SS), 256, 0, stream>>>(qk);
    dim3 grid2(SS / 256, SS / 256, BATCH);
    gemm2_kernel<<<grid2, 512, 0, stream>>>(qk, qkT, out);
}

// Round 3
// 225.068 us; speedup vs baseline: 1.0571x; 1.0161x over previous
//
#include <hip/hip_runtime.h>
#include <hip/hip_bf16.h>
#include <stdint.h>

// Re-associated pipeline:
//   qk = q@k^T (bf16, for softmax)            [gemm1, f16-MFMA, unchanged math]
//   attn = softmax(0.125*qk) in-place          [softmax, unchanged]
//   tmp = attn @ q        (via qT bf16)        [gemm2a, 128^2 m97 structure]
//   out = tmp @ k^T       (via kB bf16)        [gemm2b, 256^2 8-phase template]
// out = attn@(q@k^T) == (attn@q)@k^T exactly; halves gemm2 FLOPs and kills
// the qkT scattered-store in gemm1.
// ws: qk 33.5MB | qT 8.4MB | kB 8.4MB | tmp 8.4MB = 58.7MB.

#define SS 2048
#define DD 512
#define BATCH 4
#define NTB 8   // K tiles of 64 in gemm2b (K=512)

typedef __attribute__((ext_vector_type(8))) short short8;
typedef __attribute__((ext_vector_type(8))) _Float16 half8;
typedef __attribute__((ext_vector_type(4))) float floatx4;
typedef __attribute__((ext_vector_type(4))) float float4v;
typedef __attribute__((ext_vector_type(4))) unsigned int uintx4;

#define GLOBAL_AS const __attribute__((address_space(1)))
#define LDS_AS __attribute__((address_space(3)))

__device__ __forceinline__ float bf2f(uint32_t hbits) {
    union { uint32_t u; float f; } c; c.u = hbits << 16; return c.f;
}
__device__ __forceinline__ uint32_t f2bf_rne(float f) {
    union { float f; uint32_t u; } c; c.f = f;
    return (c.u + 0x7fffu + ((c.u >> 16) & 1u)) >> 16;
}
__device__ __forceinline__ uint32_t pk2h(float x, float y) {
    _Float16 hx = (_Float16)x, hy = (_Float16)y;   // RNE v_cvt_f16_f32
    union { _Float16 h; uint16_t u; } cx, cy;
    cx.h = hx; cy.h = hy;
    return (uint32_t)cx.u | ((uint32_t)cy.u << 16);
}

union PackU { uint32_t u[4]; short8 s8; };

// ---------------------------------------------------------------- prep
// y<8 : qT[b][d][u] = bf16(q[b][u][d])  (64x64 LDS transpose tiles)
// y==8: kB[b][t][d] = bf16(k[b][t][d])  (straight convert)
__global__ __launch_bounds__(256) void prep_kernel(
    const float* __restrict__ Q, const float* __restrict__ K,
    uint16_t* __restrict__ qT, uint16_t* __restrict__ kB)
{
    const int b   = blockIdx.z;
    const int tid = threadIdx.x;

    if (blockIdx.y == 8) {
        const float* kb_ = K + (size_t)b * SS * DD;
        uint16_t* ob = kB + (size_t)b * SS * DD;
        const int g0 = blockIdx.x * 256 + tid;   // 8192 threads, 131072 chunks
#pragma unroll
        for (int i = 0; i < 16; ++i) {
            const int g = g0 + i * 8192;
            const float4v* src = (const float4v*)(kb_ + (size_t)g * 8);
            float4v x0 = src[0], x1 = src[1];
            PackU p;
            p.u[0] = f2bf_rne(x0[0]) | (f2bf_rne(x0[1]) << 16);
            p.u[1] = f2bf_rne(x0[2]) | (f2bf_rne(x0[3]) << 16);
            p.u[2] = f2bf_rne(x1[0]) | (f2bf_rne(x1[1]) << 16);
            p.u[3] = f2bf_rne(x1[2]) | (f2bf_rne(x1[3]) << 16);
            *(short8*)(ob + (size_t)g * 8) = p.s8;
        }
        return;
    }

    const int u0 = blockIdx.x * 64;
    const int d0 = blockIdx.y * 64;
    const float* qb = Q + (size_t)b * SS * DD;
    uint16_t* qTb = qT + (size_t)b * DD * SS;

    __shared__ uint16_t T[64 * 66];   // [u-local][d-local], stride 66 (2-way max)

    {
        const int r  = tid >> 2;          // u-local 0..63
        const int c4 = (tid & 3) * 16;    // d-local chunk
        const float* src = qb + (size_t)(u0 + r) * DD + d0 + c4;
        float4v x0 = *(const float4v*)(src + 0);
        float4v x1 = *(const float4v*)(src + 4);
        float4v x2 = *(const float4v*)(src + 8);
        float4v x3 = *(const float4v*)(src + 12);
        uint32_t w0 = f2bf_rne(x0[0]) | (f2bf_rne(x0[1]) << 16);
        uint32_t w1 = f2bf_rne(x0[2]) | (f2bf_rne(x0[3]) << 16);
        uint32_t w2 = f2bf_rne(x1[0]) | (f2bf_rne(x1[1]) << 16);
        uint32_t w3 = f2bf_rne(x1[2]) | (f2bf_rne(x1[3]) << 16);
        uint32_t w4 = f2bf_rne(x2[0]) | (f2bf_rne(x2[1]) << 16);
        uint32_t w5 = f2bf_rne(x2[2]) | (f2bf_rne(x2[3]) << 16);
        uint32_t w6 = f2bf_rne(x3[0]) | (f2bf_rne(x3[1]) << 16);
        uint32_t w7 = f2bf_rne(x3[2]) | (f2bf_rne(x3[3]) << 16);
        uint32_t* tw = (uint32_t*)&T[r * 66 + c4];   // 4B-aligned (66r+c4 even)
        tw[0] = w0; tw[1] = w1; tw[2] = w2; tw[3] = w3;
        tw[4] = w4; tw[5] = w5; tw[6] = w6; tw[7] = w7;
    }
    __syncthreads();
#pragma unroll
    for (int p = 0; p < 2; ++p) {
        const int dl  = (tid >> 3) + p * 32;
        const int ul8 = (tid & 7) * 8;
        uint16_t t8[8];
#pragma unroll
        for (int j = 0; j < 8; ++j) t8[j] = T[(ul8 + j) * 66 + dl];
        PackU o;
        o.u[0] = (uint32_t)t8[0] | ((uint32_t)t8[1] << 16);
        o.u[1] = (uint32_t)t8[2] | ((uint32_t)t8[3] << 16);
        o.u[2] = (uint32_t)t8[4] | ((uint32_t)t8[5] << 16);
        o.u[3] = (uint32_t)t8[6] | ((uint32_t)t8[7] << 16);
        *(short8*)(&qTb[(size_t)(d0 + dl) * SS + u0 + ul8]) = o.s8;
    }
}

// ---------------------------------------------------------------- GEMM1
// qk[s][t] = sum_d q[s][d]*k[t][d]  via single-pass fp16 MFMA, BK=64.
// (qkT write removed; MFMA order unchanged -> qk bit-identical to prior rounds)
__global__ __launch_bounds__(256, 2) void gemm1_kernel(
    const float* __restrict__ Q, const float* __restrict__ K,
    uint16_t* __restrict__ qk)
{
    const int b  = blockIdx.z;
    const int s0 = blockIdx.y * 128;
    const int t0 = blockIdx.x * 128;
    const float* qb = Q + (size_t)b * SS * DD;
    const float* kb = K + (size_t)b * SS * DD;

    __shared__ uint16_t Ah[2 * 128 * 32];   // two BK=32 sub-tiles
    __shared__ uint16_t Bh[2 * 128 * 32];

    const int tid  = threadIdx.x;
    const int lane = tid & 63;
    const int wave = tid >> 6;
    const int wm   = wave >> 1;
    const int wn   = wave & 1;
    const int fm   = lane & 15;
    const int quad = lane >> 4;

    floatx4 acc[4][4];
#pragma unroll
    for (int i = 0; i < 4; ++i)
#pragma unroll
        for (int j = 0; j < 4; ++j)
            acc[i][j] = (floatx4)0.0f;

    const int r  = tid >> 1;          // staging row 0..127
    const int c0 = (tid & 1) * 16;    // staging col chunk (fp32 elems)
    const float* gA = qb + (size_t)(s0 + r) * DD + c0;
    const float* gB = kb + (size_t)(t0 + r) * DD + c0;

    for (int k0 = 0; k0 < DD; k0 += 64) {
        uint32_t pa[2][8], pb[2][8];
#pragma unroll
        for (int ks = 0; ks < 2; ++ks) {
            float4v a4[4], b4[4];
#pragma unroll
            for (int l = 0; l < 4; ++l) {
                a4[l] = *(const float4v*)(gA + k0 + ks * 32 + l * 4);
                b4[l] = *(const float4v*)(gB + k0 + ks * 32 + l * 4);
            }
#pragma unroll
            for (int l = 0; l < 4; ++l) {
                pa[ks][2 * l]     = pk2h(a4[l][0], a4[l][1]);
                pa[ks][2 * l + 1] = pk2h(a4[l][2], a4[l][3]);
                pb[ks][2 * l]     = pk2h(b4[l][0], b4[l][1]);
                pb[ks][2 * l + 1] = pk2h(b4[l][2], b4[l][3]);
            }
        }
        __syncthreads();   // previous iteration's LDS reads complete
#pragma unroll
        for (int ks = 0; ks < 2; ++ks) {
            PackU p;
            p.u[0]=pa[ks][0]; p.u[1]=pa[ks][1]; p.u[2]=pa[ks][2]; p.u[3]=pa[ks][3];
            *(short8*)(&Ah[ks * 4096 + r * 32 + c0]) = p.s8;
            p.u[0]=pa[ks][4]; p.u[1]=pa[ks][5]; p.u[2]=pa[ks][6]; p.u[3]=pa[ks][7];
            *(short8*)(&Ah[ks * 4096 + r * 32 + c0 + 8]) = p.s8;
            p.u[0]=pb[ks][0]; p.u[1]=pb[ks][1]; p.u[2]=pb[ks][2]; p.u[3]=pb[ks][3];
            *(short8*)(&Bh[ks * 4096 + r * 32 + c0]) = p.s8;
            p.u[0]=pb[ks][4]; p.u[1]=pb[ks][5]; p.u[2]=pb[ks][6]; p.u[3]=pb[ks][7];
            *(short8*)(&Bh[ks * 4096 + r * 32 + c0 + 8]) = p.s8;
        }
        __syncthreads();

#pragma unroll
        for (int ks = 0; ks < 2; ++ks) {
            half8 fa[4], fb[4];
#pragma unroll
            for (int mt = 0; mt < 4; ++mt)
                fa[mt] = *(const half8*)(&Ah[ks * 4096 + (wm * 64 + mt * 16 + fm) * 32 + quad * 8]);
#pragma unroll
            for (int nt = 0; nt < 4; ++nt)
                fb[nt] = *(const half8*)(&Bh[ks * 4096 + (wn * 64 + nt * 16 + fm) * 32 + quad * 8]);
#pragma unroll
            for (int mt = 0; mt < 4; ++mt)
#pragma unroll
                for (int nt = 0; nt < 4; ++nt)
                    acc[mt][nt] = __builtin_amdgcn_mfma_f32_16x16x32_f16(fa[mt], fb[nt], acc[mt][nt], 0, 0, 0);
        }
    }

    uint16_t* qkb = qk + (size_t)b * SS * SS;
#pragma unroll
    for (int mt = 0; mt < 4; ++mt) {
#pragma unroll
        for (int nt = 0; nt < 4; ++nt) {
            const int srow = s0 + wm * 64 + mt * 16 + quad * 4;
            const int tcol = t0 + wn * 64 + nt * 16 + fm;
            qkb[(size_t)(srow + 0) * SS + tcol] = (uint16_t)f2bf_rne(acc[mt][nt][0]);
            qkb[(size_t)(srow + 1) * SS + tcol] = (uint16_t)f2bf_rne(acc[mt][nt][1]);
            qkb[(size_t)(srow + 2) * SS + tcol] = (uint16_t)f2bf_rne(acc[mt][nt][2]);
            qkb[(size_t)(srow + 3) * SS + tcol] = (uint16_t)f2bf_rne(acc[mt][nt][3]);
        }
    }
}

// ---------------------------------------------------------------- softmax
// in-place: qk row -> softmax(0.125*row), bf16.
__global__ __launch_bounds__(256) void softmax_inplace(uint16_t* __restrict__ qk)
{
    const size_t row = blockIdx.x;
    uint16_t* x = qk + row * SS;
    const int tid  = threadIdx.x;
    const int lane = tid & 63;
    const int wave = tid >> 6;

    uintx4 raw = *(const uintx4*)(x + tid * 8);
    float v[8];
#pragma unroll
    for (int i = 0; i < 4; ++i) {
        uint32_t u = raw[i];
        v[2 * i]     = bf2f(u & 0xffffu) * 0.125f;
        v[2 * i + 1] = bf2f(u >> 16) * 0.125f;
    }
    float m = v[0];
#pragma unroll
    for (int j = 1; j < 8; ++j) m = fmaxf(m, v[j]);
#pragma unroll
    for (int off = 1; off < 64; off <<= 1) m = fmaxf(m, __shfl_xor(m, off, 64));
    __shared__ float red[8];
    if (lane == 0) red[wave] = m;
    __syncthreads();
    m = fmaxf(fmaxf(red[0], red[1]), fmaxf(red[2], red[3]));

    float s = 0.f;
#pragma unroll
    for (int j = 0; j < 8; ++j) { v[j] = __expf(v[j] - m); s += v[j]; }
#pragma unroll
    for (int off = 1; off < 64; off <<= 1) s += __shfl_xor(s, off, 64);
    if (lane == 0) red[4 + wave] = s;
    __syncthreads();
    s = (red[4] + red[5]) + (red[6] + red[7]);
    const float inv = 1.0f / s;
#pragma unroll
    for (int i = 0; i < 4; ++i)
        raw[i] = f2bf_rne(v[2 * i] * inv) | (f2bf_rne(v[2 * i + 1] * inv) << 16);
    *(uintx4*)(x + tid * 8) = raw;
}

// ---------------------------------------------------------------- GEMM2a
// tmp[s][d] = sum_u attn[s][u] * qT[d][u]   (M=2048, N=512, K=2048)
// 128^2 m97 structure, BK=64 as two BK=32 sub-stages, bf16 out.
__global__ __launch_bounds__(256, 2) void gemm2a_kernel(
    const uint16_t* __restrict__ attn, const uint16_t* __restrict__ qT,
    uint16_t* __restrict__ tmp)
{
    const int b  = blockIdx.z;
    const int s0 = blockIdx.y * 128;
    const int t0 = blockIdx.x * 128;   // d-dim, 0..511
    const uint16_t* ab = attn + (size_t)b * SS * SS;
    const uint16_t* bb = qT   + (size_t)b * DD * SS;   // ld = SS

    __shared__ uint16_t As[2 * 128 * 32];
    __shared__ uint16_t Bs[2 * 128 * 32];

    const int tid  = threadIdx.x;
    const int lane = tid & 63;
    const int wave = tid >> 6;
    const int wm = wave >> 1, wn = wave & 1;
    const int fm = lane & 15, quad = lane >> 4;

    floatx4 acc[4][4];
#pragma unroll
    for (int i = 0; i < 4; ++i)
#pragma unroll
        for (int j = 0; j < 4; ++j)
            acc[i][j] = (floatx4)0.0f;

    const int c0i = wave * 128 + lane;
    const int c1i = c0i + 64;
    const int rA0 = c0i >> 2, pA0 = c0i & 3;
    const int rA1 = c1i >> 2, pA1 = c1i & 3;
    const int ldsOff0 = (wave * 128) * 8;        // halfs
    const int ldsOff1 = (wave * 128 + 64) * 8;

    for (int k0 = 0; k0 < SS; k0 += 64) {
        __syncthreads();   // previous iteration's LDS reads complete
#pragma unroll
        for (int ks = 0; ks < 2; ++ks) {
            const int kc = k0 + ks * 32;
            uint16_t* asub = &As[ks * 4096];
            uint16_t* bsub = &Bs[ks * 4096];
            __builtin_amdgcn_global_load_lds(
                (GLOBAL_AS void*)(ab + (size_t)(s0 + rA0) * SS + kc + pA0 * 8),
                (LDS_AS void*)(asub + ldsOff0), 16, 0, 0);
            __builtin_amdgcn_global_load_lds(
                (GLOBAL_AS void*)(ab + (size_t)(s0 + rA1) * SS + kc + pA1 * 8),
                (LDS_AS void*)(asub + ldsOff1), 16, 0, 0);
            __builtin_amdgcn_global_load_lds(
                (GLOBAL_AS void*)(bb + (size_t)(t0 + rA0) * SS + kc + pA0 * 8),
                (LDS_AS void*)(bsub + ldsOff0), 16, 0, 0);
            __builtin_amdgcn_global_load_lds(
                (GLOBAL_AS void*)(bb + (size_t)(t0 + rA1) * SS + kc + pA1 * 8),
                (LDS_AS void*)(bsub + ldsOff1), 16, 0, 0);
        }
        __syncthreads();   // drains vmcnt -> data resident in LDS

#pragma unroll
        for (int ks = 0; ks < 2; ++ks) {
            short8 fa[4], fb[4];
#pragma unroll
            for (int mt = 0; mt < 4; ++mt)
                fa[mt] = *(const short8*)(&As[ks * 4096 + (wm * 64 + mt * 16 + fm) * 32 + quad * 8]);
#pragma unroll
            for (int nt = 0; nt < 4; ++nt)
                fb[nt] = *(const short8*)(&Bs[ks * 4096 + (wn * 64 + nt * 16 + fm) * 32 + quad * 8]);
#pragma unroll
            for (int mt = 0; mt < 4; ++mt)
#pragma unroll
                for (int nt = 0; nt < 4; ++nt)
                    acc[mt][nt] = __builtin_amdgcn_mfma_f32_16x16x32_bf16(fa[mt], fb[nt], acc[mt][nt], 0, 0, 0);
        }
    }

    uint16_t* tb = tmp + (size_t)b * SS * DD;
#pragma unroll
    for (int mt = 0; mt < 4; ++mt) {
#pragma unroll
        for (int nt = 0; nt < 4; ++nt) {
            const int srow = s0 + wm * 64 + mt * 16 + quad * 4;
            const int tcol = t0 + wn * 64 + nt * 16 + fm;
#pragma unroll
            for (int reg = 0; reg < 4; ++reg)
                tb[(size_t)(srow + reg) * DD + tcol] = (uint16_t)f2bf_rne(acc[mt][nt][reg]);
        }
    }
}

// ---------------------------------------------------------------- GEMM2b
// out[s][t] = sum_d tmp[s][d] * kB[t][d]   (M=2048, N=2048, K=512)
// 256^2 8-phase template (verified round 2), K=512 -> NTB=8, lds A/B ld=DD.
__global__ __launch_bounds__(512, 2) void gemm2b_kernel(
    const uint16_t* __restrict__ tmp, const uint16_t* __restrict__ kB,
    float* __restrict__ out)
{
    const int b  = blockIdx.z;
    const int s0 = blockIdx.y * 256;
    const int t0 = blockIdx.x * 256;
    const uint16_t* ab = tmp + (size_t)b * SS * DD;   // ld DD
    const uint16_t* bb = kB  + (size_t)b * SS * DD;   // ld DD

    __shared__ uint16_t smem[65536];

    const int tid  = threadIdx.x;
    const int lane = tid & 63;
    const int wave = tid >> 6;
    const int wm   = wave >> 2;   // 0..1  (M half)
    const int wn   = wave & 3;    // 0..3  (N quarter)
    const int fm   = lane & 15;
    const int quad = lane >> 4;

    floatx4 acc[8][4];
#pragma unroll
    for (int i = 0; i < 8; ++i)
#pragma unroll
        for (int j = 0; j < 4; ++j)
            acc[i][j] = (floatx4)0.0f;

    const int sl0  = (quad ^ (fm & 7)) * 8;          // ks=0 ; ks=1 -> sl0^32
    const int aoff = (wm * 128 + fm) * 64;
    const int boff = 32768 + (wn * 64 + fm) * 64;

    const int c0 = wave * 128 + lane;
    const int r0 = c0 >> 3;  const int l0 = ((c0 & 7) ^ (r0 & 7)) * 8;
    const int c1 = c0 + 64;
    const int r1 = c1 >> 3;  const int l1 = ((c1 & 7) ^ (r1 & 7)) * 8;
    const int ldsW = wave * 1024;

    auto STAGE_A = [&](int tt, int h) {
        uint16_t* base = &smem[(tt & 1) * 16384 + h * 8192 + ldsW];
        __builtin_amdgcn_global_load_lds(
            (GLOBAL_AS void*)(ab + (size_t)(s0 + h * 128 + r0) * DD + tt * 64 + l0),
            (LDS_AS void*)(base), 16, 0, 0);
        __builtin_amdgcn_global_load_lds(
            (GLOBAL_AS void*)(ab + (size_t)(s0 + h * 128 + r1) * DD + tt * 64 + l1),
            (LDS_AS void*)(base + 512), 16, 0, 0);
    };
    auto STAGE_B = [&](int tt, int h) {
        uint16_t* base = &smem[32768 + (tt & 1) * 16384 + h * 8192 + ldsW];
        __builtin_amdgcn_global_load_lds(
            (GLOBAL_AS void*)(bb + (size_t)(t0 + h * 128 + r0) * DD + tt * 64 + l0),
            (LDS_AS void*)(base), 16, 0, 0);
        __builtin_amdgcn_global_load_lds(
            (GLOBAL_AS void*)(bb + (size_t)(t0 + h * 128 + r1) * DD + tt * 64 + l1),
            (LDS_AS void*)(base + 512), 16, 0, 0);
    };

    STAGE_A(0, 0); STAGE_A(0, 1); STAGE_B(0, 0); STAGE_B(0, 1);
    STAGE_B(1, 0); STAGE_B(1, 1);
    asm volatile("s_waitcnt vmcnt(4)" ::: "memory");
    __builtin_amdgcn_s_barrier();

    short8 aF[4], aF2[4], bF[4][2];

    for (int t = 0; t < NTB; ++t) {
        const int abase = (t & 1) * 16384;
        const int bbase = (t & 1) * 16384;

        // ===== P1: read B(all nt, both ks) + A(m0-3, ks0) ; stage A(t+1,h0)
#pragma unroll
        for (int nt = 0; nt < 4; ++nt) {
            bF[nt][0] = *(const short8*)&smem[bbase + boff + nt * 1024 + sl0];
            bF[nt][1] = *(const short8*)&smem[bbase + boff + nt * 1024 + (sl0 ^ 32)];
        }
#pragma unroll
        for (int m = 0; m < 4; ++m)
            aF[m] = *(const short8*)&smem[abase + aoff + m * 1024 + sl0];
        if (t + 1 < NTB) STAGE_A(t + 1, 0);
        __builtin_amdgcn_s_barrier();
        asm volatile("s_waitcnt lgkmcnt(0)" ::: "memory");
        __builtin_amdgcn_s_setprio(1);
#pragma unroll
        for (int m = 0; m < 4; ++m)
#pragma unroll
            for (int nt = 0; nt < 4; ++nt)
                acc[m][nt] = __builtin_amdgcn_mfma_f32_16x16x32_bf16(aF[m], bF[nt][0], acc[m][nt], 0, 0, 0);
        __builtin_amdgcn_s_setprio(0);
        __builtin_amdgcn_s_barrier();

        // ===== P2: read A(m4-7, ks0) ; stage A(t+1,h1)
#pragma unroll
        for (int m = 0; m < 4; ++m)
            aF2[m] = *(const short8*)&smem[abase + aoff + (m + 4) * 1024 + sl0];
        if (t + 1 < NTB) STAGE_A(t + 1, 1);
        __builtin_amdgcn_s_barrier();
        asm volatile("s_waitcnt lgkmcnt(0)" ::: "memory");
        __builtin_amdgcn_s_setprio(1);
#pragma unroll
        for (int m = 0; m < 4; ++m)
#pragma unroll
            for (int nt = 0; nt < 4; ++nt)
                acc[m + 4][nt] = __builtin_amdgcn_mfma_f32_16x16x32_bf16(aF2[m], bF[nt][0], acc[m + 4][nt], 0, 0, 0);
        __builtin_amdgcn_s_setprio(0);
        __builtin_amdgcn_s_barrier();

        // ===== P3: read A(m0-3, ks1) ; stage B(t+2,h0)
#pragma unroll
        for (int m = 0; m < 4; ++m)
            aF[m] = *(const short8*)&smem[abase + aoff + m * 1024 + (sl0 ^ 32)];
        if (t + 2 < NTB) STAGE_B(t + 2, 0);
        __builtin_amdgcn_s_barrier();
        asm volatile("s_waitcnt lgkmcnt(0)" ::: "memory");
        __builtin_amdgcn_s_setprio(1);
#pragma unroll
        for (int m = 0; m < 4; ++m)
#pragma unroll
            for (int nt = 0; nt < 4; ++nt)
                acc[m][nt] = __builtin_amdgcn_mfma_f32_16x16x32_bf16(aF[m], bF[nt][1], acc[m][nt], 0, 0, 0);
        __builtin_amdgcn_s_setprio(0);
        __builtin_amdgcn_s_barrier();

        // ===== P4: read A(m4-7, ks1) ; stage B(t+2,h1) ; vmcnt
#pragma unroll
        for (int m = 0; m < 4; ++m)
            aF2[m] = *(const short8*)&smem[abase + aoff + (m + 4) * 1024 + (sl0 ^ 32)];
        if (t + 2 < NTB) {
            STAGE_B(t + 2, 1);
            asm volatile("s_waitcnt vmcnt(4)" ::: "memory");
        } else {
            asm volatile("s_waitcnt vmcnt(0)" ::: "memory");
        }
        __builtin_amdgcn_s_barrier();
        asm volatile("s_waitcnt lgkmcnt(0)" ::: "memory");
        __builtin_amdgcn_s_setprio(1);
#pragma unroll
        for (int m = 0; m < 4; ++m)
#pragma unroll
            for (int nt = 0; nt < 4; ++nt)
                acc[m + 4][nt] = __builtin_amdgcn_mfma_f32_16x16x32_bf16(aF2[m], bF[nt][1], acc[m + 4][nt], 0, 0, 0);
        __builtin_amdgcn_s_setprio(0);
        __builtin_amdgcn_s_barrier();
    }

    float* ob = out + (size_t)b * SS * SS;
#pragma unroll
    for (int mt = 0; mt < 8; ++mt) {
#pragma unroll
        for (int nt = 0; nt < 4; ++nt) {
            const int srow = s0 + wm * 128 + mt * 16 + quad * 4;
            const int tcol = t0 + wn * 64 + nt * 16 + fm;
#pragma unroll
            for (int reg = 0; reg < 4; ++reg)
                ob[(size_t)(srow + reg) * SS + tcol] = acc[mt][nt][reg];
        }
    }
}

extern "C" void kernel_launch(void* const* d_in, const int* in_sizes, int n_in,
                              void* d_out, int out_size, void* d_ws, size_t ws_size,
                              hipStream_t stream) {
    const float* q = (const float*)d_in[0];
    const float* k = (const float*)d_in[1];
    float* out = (float*)d_out;

    uint16_t* qk  = (uint16_t*)d_ws;                   // 4*2048*2048
    uint16_t* qT  = qk + (size_t)BATCH * SS * SS;      // 4*512*2048
    uint16_t* kB  = qT + (size_t)BATCH * DD * SS;      // 4*2048*512
    uint16_t* tmp = kB + (size_t)BATCH * SS * DD;      // 4*2048*512

    dim3 grid1(SS / 128, SS / 128, BATCH);
    gemm1_kernel<<<grid1, 256, 0, stream>>>(q, k, qk);
    prep_kernel<<<dim3(32, 9, BATCH), 256, 0, stream>>>(q, k, qT, kB);
    softmax_inplace<<<dim3(BATCH * SS), 256, 0, stream>>>(qk);
    gemm2a_kernel<<<dim3(DD / 128, SS / 128, BATCH), 256, 0, stream>>>(qk, qT, tmp);
    gemm2b_kernel<<<dim3(SS / 256, SS / 256, BATCH), 512, 0, stream>>>(tmp, kB, out);
}

// Round 4
// 204.926 us; speedup vs baseline: 1.1611x; 1.0983x over previous
//
#include <hip/hip_runtime.h>
#include <hip/hip_bf16.h>
#include <stdint.h>

// Re-associated pipeline, all-f16 intermediates:
//   prep : qH=f16(q) rm | kH=f16(k) rm | qT=f16(q^T)          [streaming]
//   gemm1: qk = qH @ kH^T  (f16 MFMA, 256^2 8-phase)          [qk f16]
//   softmax: attn = softmax(0.125*qk) in-place                [f16]
//   gemm2a: tmp = attn @ qT^T  (f16, 128^2 m97)               [tmp f16]
//   gemm2b: out = tmp @ kH^T   (f16, 256^2 8-phase, f32 out)
// out = attn@(q@k^T) == (attn@q)@k^T ; f16 intermediates are strictly more
// accurate than bf16 at these magnitudes (|qk|<~130, attn<=1, |tmp|<~6).
// ws: qk 33.5 | qT 8.4 | qH 8.4 | kH 8.4 | tmp 8.4 = 67.1MB.

#define SS 2048
#define DD 512
#define BATCH 4
#define NTB 8   // K tiles of 64 for K=512 (gemm1, gemm2b)

typedef __attribute__((ext_vector_type(8))) short short8;
typedef __attribute__((ext_vector_type(8))) _Float16 half8;
typedef __attribute__((ext_vector_type(4))) float floatx4;
typedef __attribute__((ext_vector_type(4))) float float4v;
typedef __attribute__((ext_vector_type(4))) unsigned int uintx4;

#define GLOBAL_AS const __attribute__((address_space(1)))
#define LDS_AS __attribute__((address_space(3)))

__device__ __forceinline__ uint32_t pk2h(float x, float y) {
    _Float16 hx = (_Float16)x, hy = (_Float16)y;   // RNE v_cvt_f16_f32
    union { _Float16 h; uint16_t u; } cx, cy;
    cx.h = hx; cy.h = hy;
    return (uint32_t)cx.u | ((uint32_t)cy.u << 16);
}
__device__ __forceinline__ float h2f(uint32_t ubits) {
    union { uint16_t u; _Float16 h; } c; c.u = (uint16_t)ubits; return (float)c.h;
}
__device__ __forceinline__ uint16_t f2h(float f) {
    union { _Float16 h; uint16_t u; } c; c.h = (_Float16)f; return c.u;
}

union PackU { uint32_t u[4]; short8 s8; };

// ---------------------------------------------------------------- prep
__global__ __launch_bounds__(256) void prep_kernel(
    const float* __restrict__ Q, const float* __restrict__ K,
    uint16_t* __restrict__ qT, uint16_t* __restrict__ qH,
    uint16_t* __restrict__ kH)
{
    const int b   = blockIdx.z;
    const int tid = threadIdx.x;

    if (blockIdx.y >= 8) {
        const float* src = (blockIdx.y == 8) ? (K + (size_t)b * SS * DD)
                                             : (Q + (size_t)b * SS * DD);
        uint16_t* dst = (blockIdx.y == 8) ? (kH + (size_t)b * SS * DD)
                                          : (qH + (size_t)b * SS * DD);
        const int g0 = blockIdx.x * 256 + tid;
#pragma unroll
        for (int i = 0; i < 16; ++i) {
            const int g = g0 + i * 8192;
            const float4v* s4 = (const float4v*)(src + (size_t)g * 8);
            float4v x0 = s4[0], x1 = s4[1];
            PackU p;
            p.u[0] = pk2h(x0[0], x0[1]);
            p.u[1] = pk2h(x0[2], x0[3]);
            p.u[2] = pk2h(x1[0], x1[1]);
            p.u[3] = pk2h(x1[2], x1[3]);
            *(short8*)(dst + (size_t)g * 8) = p.s8;
        }
        return;
    }

    const int u0 = blockIdx.x * 64;
    const int d0 = blockIdx.y * 64;
    const float* qb = Q + (size_t)b * SS * DD;
    uint16_t* qTb = qT + (size_t)b * DD * SS;

    __shared__ uint16_t T[64 * 66];

    {
        const int r  = tid >> 2;
        const int c4 = (tid & 3) * 16;
        const float* src = qb + (size_t)(u0 + r) * DD + d0 + c4;
        float4v x0 = *(const float4v*)(src + 0);
        float4v x1 = *(const float4v*)(src + 4);
        float4v x2 = *(const float4v*)(src + 8);
        float4v x3 = *(const float4v*)(src + 12);
        uint32_t* tw = (uint32_t*)&T[r * 66 + c4];
        tw[0] = pk2h(x0[0], x0[1]); tw[1] = pk2h(x0[2], x0[3]);
        tw[2] = pk2h(x1[0], x1[1]); tw[3] = pk2h(x1[2], x1[3]);
        tw[4] = pk2h(x2[0], x2[1]); tw[5] = pk2h(x2[2], x2[3]);
        tw[6] = pk2h(x3[0], x3[1]); tw[7] = pk2h(x3[2], x3[3]);
    }
    __syncthreads();
#pragma unroll
    for (int p = 0; p < 2; ++p) {
        const int dl  = (tid >> 3) + p * 32;
        const int ul8 = (tid & 7) * 8;
        uint16_t t8[8];
#pragma unroll
        for (int j = 0; j < 8; ++j) t8[j] = T[(ul8 + j) * 66 + dl];
        PackU o;
        o.u[0] = (uint32_t)t8[0] | ((uint32_t)t8[1] << 16);
        o.u[1] = (uint32_t)t8[2] | ((uint32_t)t8[3] << 16);
        o.u[2] = (uint32_t)t8[4] | ((uint32_t)t8[5] << 16);
        o.u[3] = (uint32_t)t8[6] | ((uint32_t)t8[7] << 16);
        *(short8*)(&qTb[(size_t)(d0 + dl) * SS + u0 + ul8]) = o.s8;
    }
}

// ---------------------------------------------------------------- GEMM1
// qk[s][t] = sum_d qH[s][d]*kH[t][d] — 256^2 8-phase f16, NTB=8, f16 out.
__global__ __launch_bounds__(512, 2) void gemm1_kernel(
    const uint16_t* __restrict__ qH, const uint16_t* __restrict__ kH,
    uint16_t* __restrict__ qk)
{
    const int b  = blockIdx.z;
    const int s0 = blockIdx.y * 256;
    const int t0 = blockIdx.x * 256;
    const uint16_t* ab = qH + (size_t)b * SS * DD;
    const uint16_t* bb = kH + (size_t)b * SS * DD;

    __shared__ uint16_t smem[65536];

    const int tid  = threadIdx.x;
    const int lane = tid & 63;
    const int wave = tid >> 6;
    const int wm   = wave >> 2;
    const int wn   = wave & 3;
    const int fm   = lane & 15;
    const int quad = lane >> 4;

    floatx4 acc[8][4];
#pragma unroll
    for (int i = 0; i < 8; ++i)
#pragma unroll
        for (int j = 0; j < 4; ++j)
            acc[i][j] = (floatx4)0.0f;

    const int sl0  = (quad ^ (fm & 7)) * 8;
    const int aoff = (wm * 128 + fm) * 64;
    const int boff = 32768 + (wn * 64 + fm) * 64;

    const int c0 = wave * 128 + lane;
    const int r0 = c0 >> 3;  const int l0 = ((c0 & 7) ^ (r0 & 7)) * 8;
    const int c1 = c0 + 64;
    const int r1 = c1 >> 3;  const int l1 = ((c1 & 7) ^ (r1 & 7)) * 8;
    const int ldsW = wave * 1024;

    auto STAGE_A = [&](int tt, int h) {
        uint16_t* base = &smem[(tt & 1) * 16384 + h * 8192 + ldsW];
        __builtin_amdgcn_global_load_lds(
            (GLOBAL_AS void*)(ab + (size_t)(s0 + h * 128 + r0) * DD + tt * 64 + l0),
            (LDS_AS void*)(base), 16, 0, 0);
        __builtin_amdgcn_global_load_lds(
            (GLOBAL_AS void*)(ab + (size_t)(s0 + h * 128 + r1) * DD + tt * 64 + l1),
            (LDS_AS void*)(base + 512), 16, 0, 0);
    };
    auto STAGE_B = [&](int tt, int h) {
        uint16_t* base = &smem[32768 + (tt & 1) * 16384 + h * 8192 + ldsW];
        __builtin_amdgcn_global_load_lds(
            (GLOBAL_AS void*)(bb + (size_t)(t0 + h * 128 + r0) * DD + tt * 64 + l0),
            (LDS_AS void*)(base), 16, 0, 0);
        __builtin_amdgcn_global_load_lds(
            (GLOBAL_AS void*)(bb + (size_t)(t0 + h * 128 + r1) * DD + tt * 64 + l1),
            (LDS_AS void*)(base + 512), 16, 0, 0);
    };

    STAGE_A(0, 0); STAGE_A(0, 1); STAGE_B(0, 0); STAGE_B(0, 1);
    STAGE_B(1, 0); STAGE_B(1, 1);
    asm volatile("s_waitcnt vmcnt(4)" ::: "memory");
    __builtin_amdgcn_s_barrier();

    half8 aF[4], aF2[4], bF[4][2];

    for (int t = 0; t < NTB; ++t) {
        const int abase = (t & 1) * 16384;
        const int bbase = (t & 1) * 16384;

#pragma unroll
        for (int nt = 0; nt < 4; ++nt) {
            bF[nt][0] = *(const half8*)&smem[bbase + boff + nt * 1024 + sl0];
            bF[nt][1] = *(const half8*)&smem[bbase + boff + nt * 1024 + (sl0 ^ 32)];
        }
#pragma unroll
        for (int m = 0; m < 4; ++m)
            aF[m] = *(const half8*)&smem[abase + aoff + m * 1024 + sl0];
        if (t + 1 < NTB) STAGE_A(t + 1, 0);
        __builtin_amdgcn_s_barrier();
        asm volatile("s_waitcnt lgkmcnt(0)" ::: "memory");
        __builtin_amdgcn_s_setprio(1);
#pragma unroll
        for (int m = 0; m < 4; ++m)
#pragma unroll
            for (int nt = 0; nt < 4; ++nt)
                acc[m][nt] = __builtin_amdgcn_mfma_f32_16x16x32_f16(aF[m], bF[nt][0], acc[m][nt], 0, 0, 0);
        __builtin_amdgcn_s_setprio(0);
        __builtin_amdgcn_s_barrier();

#pragma unroll
        for (int m = 0; m < 4; ++m)
            aF2[m] = *(const half8*)&smem[abase + aoff + (m + 4) * 1024 + sl0];
        if (t + 1 < NTB) STAGE_A(t + 1, 1);
        __builtin_amdgcn_s_barrier();
        asm volatile("s_waitcnt lgkmcnt(0)" ::: "memory");
        __builtin_amdgcn_s_setprio(1);
#pragma unroll
        for (int m = 0; m < 4; ++m)
#pragma unroll
            for (int nt = 0; nt < 4; ++nt)
                acc[m + 4][nt] = __builtin_amdgcn_mfma_f32_16x16x32_f16(aF2[m], bF[nt][0], acc[m + 4][nt], 0, 0, 0);
        __builtin_amdgcn_s_setprio(0);
        __builtin_amdgcn_s_barrier();

#pragma unroll
        for (int m = 0; m < 4; ++m)
            aF[m] = *(const half8*)&smem[abase + aoff + m * 1024 + (sl0 ^ 32)];
        if (t + 2 < NTB) STAGE_B(t + 2, 0);
        __builtin_amdgcn_s_barrier();
        asm volatile("s_waitcnt lgkmcnt(0)" ::: "memory");
        __builtin_amdgcn_s_setprio(1);
#pragma unroll
        for (int m = 0; m < 4; ++m)
#pragma unroll
            for (int nt = 0; nt < 4; ++nt)
                acc[m][nt] = __builtin_amdgcn_mfma_f32_16x16x32_f16(aF[m], bF[nt][1], acc[m][nt], 0, 0, 0);
        __builtin_amdgcn_s_setprio(0);
        __builtin_amdgcn_s_barrier();

#pragma unroll
        for (int m = 0; m < 4; ++m)
            aF2[m] = *(const half8*)&smem[abase + aoff + (m + 4) * 1024 + (sl0 ^ 32)];
        if (t + 2 < NTB) {
            STAGE_B(t + 2, 1);
            asm volatile("s_waitcnt vmcnt(4)" ::: "memory");
        } else {
            asm volatile("s_waitcnt vmcnt(0)" ::: "memory");
        }
        __builtin_amdgcn_s_barrier();
        asm volatile("s_waitcnt lgkmcnt(0)" ::: "memory");
        __builtin_amdgcn_s_setprio(1);
#pragma unroll
        for (int m = 0; m < 4; ++m)
#pragma unroll
            for (int nt = 0; nt < 4; ++nt)
                acc[m + 4][nt] = __builtin_amdgcn_mfma_f32_16x16x32_f16(aF2[m], bF[nt][1], acc[m + 4][nt], 0, 0, 0);
        __builtin_amdgcn_s_setprio(0);
        __builtin_amdgcn_s_barrier();
    }

    uint16_t* ob = qk + (size_t)b * SS * SS;
#pragma unroll
    for (int mt = 0; mt < 8; ++mt) {
#pragma unroll
        for (int nt = 0; nt < 4; ++nt) {
            const int srow = s0 + wm * 128 + mt * 16 + quad * 4;
            const int tcol = t0 + wn * 64 + nt * 16 + fm;
#pragma unroll
            for (int reg = 0; reg < 4; ++reg)
                ob[(size_t)(srow + reg) * SS + tcol] = f2h(acc[mt][nt][reg]);
        }
    }
}

// ---------------------------------------------------------------- softmax
__global__ __launch_bounds__(256) void softmax_inplace(uint16_t* __restrict__ qk)
{
    const size_t row = blockIdx.x;
    uint16_t* x = qk + row * SS;
    const int tid  = threadIdx.x;
    const int lane = tid & 63;
    const int wave = tid >> 6;

    uintx4 raw = *(const uintx4*)(x + tid * 8);
    float v[8];
#pragma unroll
    for (int i = 0; i < 4; ++i) {
        uint32_t u = raw[i];
        v[2 * i]     = h2f(u & 0xffffu) * 0.125f;
        v[2 * i + 1] = h2f(u >> 16) * 0.125f;
    }
    float m = v[0];
#pragma unroll
    for (int j = 1; j < 8; ++j) m = fmaxf(m, v[j]);
#pragma unroll
    for (int off = 1; off < 64; off <<= 1) m = fmaxf(m, __shfl_xor(m, off, 64));
    __shared__ float red[8];
    if (lane == 0) red[wave] = m;
    __syncthreads();
    m = fmaxf(fmaxf(red[0], red[1]), fmaxf(red[2], red[3]));

    float s = 0.f;
#pragma unroll
    for (int j = 0; j < 8; ++j) { v[j] = __expf(v[j] - m); s += v[j]; }
#pragma unroll
    for (int off = 1; off < 64; off <<= 1) s += __shfl_xor(s, off, 64);
    if (lane == 0) red[4 + wave] = s;
    __syncthreads();
    s = (red[4] + red[5]) + (red[6] + red[7]);
    const float inv = 1.0f / s;
#pragma unroll
    for (int i = 0; i < 4; ++i)
        raw[i] = pk2h(v[2 * i] * inv, v[2 * i + 1] * inv);
    *(uintx4*)(x + tid * 8) = raw;
}

// ---------------------------------------------------------------- GEMM2a
// tmp[s][d] = sum_u attn[s][u] * qT[d][u]  (f16, 128^2 m97, f16 out)
__global__ __launch_bounds__(256, 2) void gemm2a_kernel(
    const uint16_t* __restrict__ attn, const uint16_t* __restrict__ qT,
    uint16_t* __restrict__ tmp)
{
    const int b  = blockIdx.z;
    const int s0 = blockIdx.y * 128;
    const int t0 = blockIdx.x * 128;
    const uint16_t* ab = attn + (size_t)b * SS * SS;
    const uint16_t* bb = qT   + (size_t)b * DD * SS;

    __shared__ uint16_t As[2 * 128 * 32];
    __shared__ uint16_t Bs[2 * 128 * 32];

    const int tid  = threadIdx.x;
    const int lane = tid & 63;
    const int wave = tid >> 6;
    const int wm = wave >> 1, wn = wave & 1;
    const int fm = lane & 15, quad = lane >> 4;

    floatx4 acc[4][4];
#pragma unroll
    for (int i = 0; i < 4; ++i)
#pragma unroll
        for (int j = 0; j < 4; ++j)
            acc[i][j] = (floatx4)0.0f;

    const int c0i = wave * 128 + lane;
    const int c1i = c0i + 64;
    const int rA0 = c0i >> 2, pA0 = c0i & 3;
    const int rA1 = c1i >> 2, pA1 = c1i & 3;
    const int ldsOff0 = (wave * 128) * 8;
    const int ldsOff1 = (wave * 128 + 64) * 8;

    for (int k0 = 0; k0 < SS; k0 += 64) {
        __syncthreads();
#pragma unroll
        for (int ks = 0; ks < 2; ++ks) {
            const int kc = k0 + ks * 32;
            uint16_t* asub = &As[ks * 4096];
            uint16_t* bsub = &Bs[ks * 4096];
            __builtin_amdgcn_global_load_lds(
                (GLOBAL_AS void*)(ab + (size_t)(s0 + rA0) * SS + kc + pA0 * 8),
                (LDS_AS void*)(asub + ldsOff0), 16, 0, 0);
            __builtin_amdgcn_global_load_lds(
                (GLOBAL_AS void*)(ab + (size_t)(s0 + rA1) * SS + kc + pA1 * 8),
                (LDS_AS void*)(asub + ldsOff1), 16, 0, 0);
            __builtin_amdgcn_global_load_lds(
                (GLOBAL_AS void*)(bb + (size_t)(t0 + rA0) * SS + kc + pA0 * 8),
                (LDS_AS void*)(bsub + ldsOff0), 16, 0, 0);
            __builtin_amdgcn_global_load_lds(
                (GLOBAL_AS void*)(bb + (size_t)(t0 + rA1) * SS + kc + pA1 * 8),
                (LDS_AS void*)(bsub + ldsOff1), 16, 0, 0);
        }
        __syncthreads();

#pragma unroll
        for (int ks = 0; ks < 2; ++ks) {
            half8 fa[4], fb[4];
#pragma unroll
            for (int mt = 0; mt < 4; ++mt)
                fa[mt] = *(const half8*)(&As[ks * 4096 + (wm * 64 + mt * 16 + fm) * 32 + quad * 8]);
#pragma unroll
            for (int nt = 0; nt < 4; ++nt)
                fb[nt] = *(const half8*)(&Bs[ks * 4096 + (wn * 64 + nt * 16 + fm) * 32 + quad * 8]);
#pragma unroll
            for (int mt = 0; mt < 4; ++mt)
#pragma unroll
                for (int nt = 0; nt < 4; ++nt)
                    acc[mt][nt] = __builtin_amdgcn_mfma_f32_16x16x32_f16(fa[mt], fb[nt], acc[mt][nt], 0, 0, 0);
        }
    }

    uint16_t* tb = tmp + (size_t)b * SS * DD;
#pragma unroll
    for (int mt = 0; mt < 4; ++mt) {
#pragma unroll
        for (int nt = 0; nt < 4; ++nt) {
            const int srow = s0 + wm * 64 + mt * 16 + quad * 4;
            const int tcol = t0 + wn * 64 + nt * 16 + fm;
#pragma unroll
            for (int reg = 0; reg < 4; ++reg)
                tb[(size_t)(srow + reg) * DD + tcol] = f2h(acc[mt][nt][reg]);
        }
    }
}

// ---------------------------------------------------------------- GEMM2b
// out[s][t] = sum_d tmp[s][d] * kH[t][d]  (f16, 256^2 8-phase, f32 out)
__global__ __launch_bounds__(512, 2) void gemm2b_kernel(
    const uint16_t* __restrict__ tmp, const uint16_t* __restrict__ kH,
    float* __restrict__ out)
{
    const int b  = blockIdx.z;
    const int s0 = blockIdx.y * 256;
    const int t0 = blockIdx.x * 256;
    const uint16_t* ab = tmp + (size_t)b * SS * DD;
    const uint16_t* bb = kH  + (size_t)b * SS * DD;

    __shared__ uint16_t smem[65536];

    const int tid  = threadIdx.x;
    const int lane = tid & 63;
    const int wave = tid >> 6;
    const int wm   = wave >> 2;
    const int wn   = wave & 3;
    const int fm   = lane & 15;
    const int quad = lane >> 4;

    floatx4 acc[8][4];
#pragma unroll
    for (int i = 0; i < 8; ++i)
#pragma unroll
        for (int j = 0; j < 4; ++j)
            acc[i][j] = (floatx4)0.0f;

    const int sl0  = (quad ^ (fm & 7)) * 8;
    const int aoff = (wm * 128 + fm) * 64;
    const int boff = 32768 + (wn * 64 + fm) * 64;

    const int c0 = wave * 128 + lane;
    const int r0 = c0 >> 3;  const int l0 = ((c0 & 7) ^ (r0 & 7)) * 8;
    const int c1 = c0 + 64;
    const int r1 = c1 >> 3;  const int l1 = ((c1 & 7) ^ (r1 & 7)) * 8;
    const int ldsW = wave * 1024;

    auto STAGE_A = [&](int tt, int h) {
        uint16_t* base = &smem[(tt & 1) * 16384 + h * 8192 + ldsW];
        __builtin_amdgcn_global_load_lds(
            (GLOBAL_AS void*)(ab + (size_t)(s0 + h * 128 + r0) * DD + tt * 64 + l0),
            (LDS_AS void*)(base), 16, 0, 0);
        __builtin_amdgcn_global_load_lds(
            (GLOBAL_AS void*)(ab + (size_t)(s0 + h * 128 + r1) * DD + tt * 64 + l1),
            (LDS_AS void*)(base + 512), 16, 0, 0);
    };
    auto STAGE_B = [&](int tt, int h) {
        uint16_t* base = &smem[32768 + (tt & 1) * 16384 + h * 8192 + ldsW];
        __builtin_amdgcn_global_load_lds(
            (GLOBAL_AS void*)(bb + (size_t)(t0 + h * 128 + r0) * DD + tt * 64 + l0),
            (LDS_AS void*)(base), 16, 0, 0);
        __builtin_amdgcn_global_load_lds(
            (GLOBAL_AS void*)(bb + (size_t)(t0 + h * 128 + r1) * DD + tt * 64 + l1),
            (LDS_AS void*)(base + 512), 16, 0, 0);
    };

    STAGE_A(0, 0); STAGE_A(0, 1); STAGE_B(0, 0); STAGE_B(0, 1);
    STAGE_B(1, 0); STAGE_B(1, 1);
    asm volatile("s_waitcnt vmcnt(4)" ::: "memory");
    __builtin_amdgcn_s_barrier();

    half8 aF[4], aF2[4], bF[4][2];

    for (int t = 0; t < NTB; ++t) {
        const int abase = (t & 1) * 16384;
        const int bbase = (t & 1) * 16384;

#pragma unroll
        for (int nt = 0; nt < 4; ++nt) {
            bF[nt][0] = *(const half8*)&smem[bbase + boff + nt * 1024 + sl0];
            bF[nt][1] = *(const half8*)&smem[bbase + boff + nt * 1024 + (sl0 ^ 32)];
        }
#pragma unroll
        for (int m = 0; m < 4; ++m)
            aF[m] = *(const half8*)&smem[abase + aoff + m * 1024 + sl0];
        if (t + 1 < NTB) STAGE_A(t + 1, 0);
        __builtin_amdgcn_s_barrier();
        asm volatile("s_waitcnt lgkmcnt(0)" ::: "memory");
        __builtin_amdgcn_s_setprio(1);
#pragma unroll
        for (int m = 0; m < 4; ++m)
#pragma unroll
            for (int nt = 0; nt < 4; ++nt)
                acc[m][nt] = __builtin_amdgcn_mfma_f32_16x16x32_f16(aF[m], bF[nt][0], acc[m][nt], 0, 0, 0);
        __builtin_amdgcn_s_setprio(0);
        __builtin_amdgcn_s_barrier();

#pragma unroll
        for (int m = 0; m < 4; ++m)
            aF2[m] = *(const half8*)&smem[abase + aoff + (m + 4) * 1024 + sl0];
        if (t + 1 < NTB) STAGE_A(t + 1, 1);
        __builtin_amdgcn_s_barrier();
        asm volatile("s_waitcnt lgkmcnt(0)" ::: "memory");
        __builtin_amdgcn_s_setprio(1);
#pragma unroll
        for (int m = 0; m < 4; ++m)
#pragma unroll
            for (int nt = 0; nt < 4; ++nt)
                acc[m + 4][nt] = __builtin_amdgcn_mfma_f32_16x16x32_f16(aF2[m], bF[nt][0], acc[m + 4][nt], 0, 0, 0);
        __builtin_amdgcn_s_setprio(0);
        __builtin_amdgcn_s_barrier();

#pragma unroll
        for (int m = 0; m < 4; ++m)
            aF[m] = *(const half8*)&smem[abase + aoff + m * 1024 + (sl0 ^ 32)];
        if (t + 2 < NTB) STAGE_B(t + 2, 0);
        __builtin_amdgcn_s_barrier();
        asm volatile("s_waitcnt lgkmcnt(0)" ::: "memory");
        __builtin_amdgcn_s_setprio(1);
#pragma unroll
        for (int m = 0; m < 4; ++m)
#pragma unroll
            for (int nt = 0; nt < 4; ++nt)
                acc[m][nt] = __builtin_amdgcn_mfma_f32_16x16x32_f16(aF[m], bF[nt][1], acc[m][nt], 0, 0, 0);
        __builtin_amdgcn_s_setprio(0);
        __builtin_amdgcn_s_barrier();

#pragma unroll
        for (int m = 0; m < 4; ++m)
            aF2[m] = *(const half8*)&smem[abase + aoff + (m + 4) * 1024 + (sl0 ^ 32)];
        if (t + 2 < NTB) {
            STAGE_B(t + 2, 1);
            asm volatile("s_waitcnt vmcnt(4)" ::: "memory");
        } else {
            asm volatile("s_waitcnt vmcnt(0)" ::: "memory");
        }
        __builtin_amdgcn_s_barrier();
        asm volatile("s_waitcnt lgkmcnt(0)" ::: "memory");
        __builtin_amdgcn_s_setprio(1);
#pragma unroll
        for (int m = 0; m < 4; ++m)
#pragma unroll
            for (int nt = 0; nt < 4; ++nt)
                acc[m + 4][nt] = __builtin_amdgcn_mfma_f32_16x16x32_f16(aF2[m], bF[nt][1], acc[m + 4][nt], 0, 0, 0);
        __builtin_amdgcn_s_setprio(0);
        __builtin_amdgcn_s_barrier();
    }

    float* ob = out + (size_t)b * SS * SS;
#pragma unroll
    for (int mt = 0; mt < 8; ++mt) {
#pragma unroll
        for (int nt = 0; nt < 4; ++nt) {
            const int srow = s0 + wm * 128 + mt * 16 + quad * 4;
            const int tcol = t0 + wn * 64 + nt * 16 + fm;
#pragma unroll
            for (int reg = 0; reg < 4; ++reg)
                ob[(size_t)(srow + reg) * SS + tcol] = acc[mt][nt][reg];
        }
    }
}

extern "C" void kernel_launch(void* const* d_in, const int* in_sizes, int n_in,
                              void* d_out, int out_size, void* d_ws, size_t ws_size,
                              hipStream_t stream) {
    const float* q = (const float*)d_in[0];
    const float* k = (const float*)d_in[1];
    float* out = (float*)d_out;

    uint16_t* qk  = (uint16_t*)d_ws;                   // 4*2048*2048
    uint16_t* qT  = qk + (size_t)BATCH * SS * SS;      // 4*512*2048
    uint16_t* qH  = qT + (size_t)BATCH * DD * SS;      // 4*2048*512
    uint16_t* kH  = qH + (size_t)BATCH * SS * DD;      // 4*2048*512
    uint16_t* tmp = kH + (size_t)BATCH * SS * DD;      // 4*2048*512

    prep_kernel<<<dim3(32, 10, BATCH), 256, 0, stream>>>(q, k, qT, qH, kH);
    gemm1_kernel<<<dim3(SS / 256, SS / 256, BATCH), 512, 0, stream>>>(qH, kH, qk);
    softmax_inplace<<<dim3(BATCH * SS), 256, 0, stream>>>(qk);
    gemm2a_kernel<<<dim3(DD / 128, SS / 128, BATCH), 256, 0, stream>>>(qk, qT, tmp);
    gemm2b_kernel<<<dim3(SS / 256, SS / 256, BATCH), 512, 0, stream>>>(tmp, kH, out);
}

// Round 6
// 186.707 us; speedup vs baseline: 1.2743x; 1.0976x over previous
//
#include <hip/hip_runtime.h>
#include <hip/hip_bf16.h>
#include <stdint.h>

// Re-associated pipeline, all-f16 intermediates:
//   prep : qH=f16(q) rm | kH=f16(k) rm | qT=f16(q^T)          [streaming]
//   gemm1: qk = qH @ kH^T  (f16 MFMA, 256^2 8-phase)          [qk f16]
//   softmax: attn = softmax(0.125*qk) in-place                [f16]
//   gemm2a: tmp = attn @ qT^T  (f16, 128^2 2-phase pipelined) [tmp f16]
//   gemm2b: out = tmp @ kH^T   (f16, 256^2 8-phase, f32 out)
// Round 7: fix gemm2a staging — round 6 staged only 512 of 1024 16B chunks
// per tile (rows 64-127 uninitialized -> NaN). Now 2 gload_lds per operand
// per thread (chunks tid and tid+512); vmcnt counts scaled to 4 loads/tile.
// MFMA accumulation order bit-identical to round 5's gemm2a -> absmax 0.5.

#define SS 2048
#define DD 512
#define BATCH 4
#define NTB 8    // K tiles of 64 for K=512 (gemm1, gemm2b)
#define NT2A 32  // K tiles of 64 for K=2048 (gemm2a)

typedef __attribute__((ext_vector_type(8))) short short8;
typedef __attribute__((ext_vector_type(8))) _Float16 half8;
typedef __attribute__((ext_vector_type(4))) float floatx4;
typedef __attribute__((ext_vector_type(4))) float float4v;
typedef __attribute__((ext_vector_type(4))) unsigned int uintx4;

#define GLOBAL_AS const __attribute__((address_space(1)))
#define LDS_AS __attribute__((address_space(3)))

__device__ __forceinline__ uint32_t pk2h(float x, float y) {
    _Float16 hx = (_Float16)x, hy = (_Float16)y;   // RNE v_cvt_f16_f32
    union { _Float16 h; uint16_t u; } cx, cy;
    cx.h = hx; cy.h = hy;
    return (uint32_t)cx.u | ((uint32_t)cy.u << 16);
}
__device__ __forceinline__ float h2f(uint32_t ubits) {
    union { uint16_t u; _Float16 h; } c; c.u = (uint16_t)ubits; return (float)c.h;
}
__device__ __forceinline__ uint16_t f2h(float f) {
    union { _Float16 h; uint16_t u; } c; c.h = (_Float16)f; return c.u;
}

union PackU { uint32_t u[4]; short8 s8; };

// ---------------------------------------------------------------- prep
__global__ __launch_bounds__(256) void prep_kernel(
    const float* __restrict__ Q, const float* __restrict__ K,
    uint16_t* __restrict__ qT, uint16_t* __restrict__ qH,
    uint16_t* __restrict__ kH)
{
    const int b   = blockIdx.z;
    const int tid = threadIdx.x;

    if (blockIdx.y >= 8) {
        const float* src = (blockIdx.y == 8) ? (K + (size_t)b * SS * DD)
                                             : (Q + (size_t)b * SS * DD);
        uint16_t* dst = (blockIdx.y == 8) ? (kH + (size_t)b * SS * DD)
                                          : (qH + (size_t)b * SS * DD);
        const int g0 = blockIdx.x * 256 + tid;
#pragma unroll
        for (int i = 0; i < 16; ++i) {
            const int g = g0 + i * 8192;
            const float4v* s4 = (const float4v*)(src + (size_t)g * 8);
            float4v x0 = s4[0], x1 = s4[1];
            PackU p;
            p.u[0] = pk2h(x0[0], x0[1]);
            p.u[1] = pk2h(x0[2], x0[3]);
            p.u[2] = pk2h(x1[0], x1[1]);
            p.u[3] = pk2h(x1[2], x1[3]);
            *(short8*)(dst + (size_t)g * 8) = p.s8;
        }
        return;
    }

    const int u0 = blockIdx.x * 64;
    const int d0 = blockIdx.y * 64;
    const float* qb = Q + (size_t)b * SS * DD;
    uint16_t* qTb = qT + (size_t)b * DD * SS;

    __shared__ uint16_t T[64 * 66];

    {
        const int r  = tid >> 2;
        const int c4 = (tid & 3) * 16;
        const float* src = qb + (size_t)(u0 + r) * DD + d0 + c4;
        float4v x0 = *(const float4v*)(src + 0);
        float4v x1 = *(const float4v*)(src + 4);
        float4v x2 = *(const float4v*)(src + 8);
        float4v x3 = *(const float4v*)(src + 12);
        uint32_t* tw = (uint32_t*)&T[r * 66 + c4];
        tw[0] = pk2h(x0[0], x0[1]); tw[1] = pk2h(x0[2], x0[3]);
        tw[2] = pk2h(x1[0], x1[1]); tw[3] = pk2h(x1[2], x1[3]);
        tw[4] = pk2h(x2[0], x2[1]); tw[5] = pk2h(x2[2], x2[3]);
        tw[6] = pk2h(x3[0], x3[1]); tw[7] = pk2h(x3[2], x3[3]);
    }
    __syncthreads();
#pragma unroll
    for (int p = 0; p < 2; ++p) {
        const int dl  = (tid >> 3) + p * 32;
        const int ul8 = (tid & 7) * 8;
        uint16_t t8[8];
#pragma unroll
        for (int j = 0; j < 8; ++j) t8[j] = T[(ul8 + j) * 66 + dl];
        PackU o;
        o.u[0] = (uint32_t)t8[0] | ((uint32_t)t8[1] << 16);
        o.u[1] = (uint32_t)t8[2] | ((uint32_t)t8[3] << 16);
        o.u[2] = (uint32_t)t8[4] | ((uint32_t)t8[5] << 16);
        o.u[3] = (uint32_t)t8[6] | ((uint32_t)t8[7] << 16);
        *(short8*)(&qTb[(size_t)(d0 + dl) * SS + u0 + ul8]) = o.s8;
    }
}

// ---------------------------------------------------------------- GEMM1
// qk[s][t] = sum_d qH[s][d]*kH[t][d] — 256^2 8-phase f16, NTB=8, f16 out.
__global__ __launch_bounds__(512, 2) void gemm1_kernel(
    const uint16_t* __restrict__ qH, const uint16_t* __restrict__ kH,
    uint16_t* __restrict__ qk)
{
    const int b  = blockIdx.z;
    const int s0 = blockIdx.y * 256;
    const int t0 = blockIdx.x * 256;
    const uint16_t* ab = qH + (size_t)b * SS * DD;
    const uint16_t* bb = kH + (size_t)b * SS * DD;

    __shared__ uint16_t smem[65536];

    const int tid  = threadIdx.x;
    const int lane = tid & 63;
    const int wave = tid >> 6;
    const int wm   = wave >> 2;
    const int wn   = wave & 3;
    const int fm   = lane & 15;
    const int quad = lane >> 4;

    floatx4 acc[8][4];
#pragma unroll
    for (int i = 0; i < 8; ++i)
#pragma unroll
        for (int j = 0; j < 4; ++j)
            acc[i][j] = (floatx4)0.0f;

    const int sl0  = (quad ^ (fm & 7)) * 8;
    const int aoff = (wm * 128 + fm) * 64;
    const int boff = 32768 + (wn * 64 + fm) * 64;

    const int c0 = wave * 128 + lane;
    const int r0 = c0 >> 3;  const int l0 = ((c0 & 7) ^ (r0 & 7)) * 8;
    const int c1 = c0 + 64;
    const int r1 = c1 >> 3;  const int l1 = ((c1 & 7) ^ (r1 & 7)) * 8;
    const int ldsW = wave * 1024;

    auto STAGE_A = [&](int tt, int h) {
        uint16_t* base = &smem[(tt & 1) * 16384 + h * 8192 + ldsW];
        __builtin_amdgcn_global_load_lds(
            (GLOBAL_AS void*)(ab + (size_t)(s0 + h * 128 + r0) * DD + tt * 64 + l0),
            (LDS_AS void*)(base), 16, 0, 0);
        __builtin_amdgcn_global_load_lds(
            (GLOBAL_AS void*)(ab + (size_t)(s0 + h * 128 + r1) * DD + tt * 64 + l1),
            (LDS_AS void*)(base + 512), 16, 0, 0);
    };
    auto STAGE_B = [&](int tt, int h) {
        uint16_t* base = &smem[32768 + (tt & 1) * 16384 + h * 8192 + ldsW];
        __builtin_amdgcn_global_load_lds(
            (GLOBAL_AS void*)(bb + (size_t)(t0 + h * 128 + r0) * DD + tt * 64 + l0),
            (LDS_AS void*)(base), 16, 0, 0);
        __builtin_amdgcn_global_load_lds(
            (GLOBAL_AS void*)(bb + (size_t)(t0 + h * 128 + r1) * DD + tt * 64 + l1),
            (LDS_AS void*)(base + 512), 16, 0, 0);
    };

    STAGE_A(0, 0); STAGE_A(0, 1); STAGE_B(0, 0); STAGE_B(0, 1);
    STAGE_B(1, 0); STAGE_B(1, 1);
    asm volatile("s_waitcnt vmcnt(4)" ::: "memory");
    __builtin_amdgcn_s_barrier();

    half8 aF[4], aF2[4], bF[4][2];

    for (int t = 0; t < NTB; ++t) {
        const int abase = (t & 1) * 16384;
        const int bbase = (t & 1) * 16384;

#pragma unroll
        for (int nt = 0; nt < 4; ++nt) {
            bF[nt][0] = *(const half8*)&smem[bbase + boff + nt * 1024 + sl0];
            bF[nt][1] = *(const half8*)&smem[bbase + boff + nt * 1024 + (sl0 ^ 32)];
        }
#pragma unroll
        for (int m = 0; m < 4; ++m)
            aF[m] = *(const half8*)&smem[abase + aoff + m * 1024 + sl0];
        if (t + 1 < NTB) STAGE_A(t + 1, 0);
        __builtin_amdgcn_s_barrier();
        asm volatile("s_waitcnt lgkmcnt(0)" ::: "memory");
        __builtin_amdgcn_s_setprio(1);
#pragma unroll
        for (int m = 0; m < 4; ++m)
#pragma unroll
            for (int nt = 0; nt < 4; ++nt)
                acc[m][nt] = __builtin_amdgcn_mfma_f32_16x16x32_f16(aF[m], bF[nt][0], acc[m][nt], 0, 0, 0);
        __builtin_amdgcn_s_setprio(0);
        __builtin_amdgcn_s_barrier();

#pragma unroll
        for (int m = 0; m < 4; ++m)
            aF2[m] = *(const half8*)&smem[abase + aoff + (m + 4) * 1024 + sl0];
        if (t + 1 < NTB) STAGE_A(t + 1, 1);
        __builtin_amdgcn_s_barrier();
        asm volatile("s_waitcnt lgkmcnt(0)" ::: "memory");
        __builtin_amdgcn_s_setprio(1);
#pragma unroll
        for (int m = 0; m < 4; ++m)
#pragma unroll
            for (int nt = 0; nt < 4; ++nt)
                acc[m + 4][nt] = __builtin_amdgcn_mfma_f32_16x16x32_f16(aF2[m], bF[nt][0], acc[m + 4][nt], 0, 0, 0);
        __builtin_amdgcn_s_setprio(0);
        __builtin_amdgcn_s_barrier();

#pragma unroll
        for (int m = 0; m < 4; ++m)
            aF[m] = *(const half8*)&smem[abase + aoff + m * 1024 + (sl0 ^ 32)];
        if (t + 2 < NTB) STAGE_B(t + 2, 0);
        __builtin_amdgcn_s_barrier();
        asm volatile("s_waitcnt lgkmcnt(0)" ::: "memory");
        __builtin_amdgcn_s_setprio(1);
#pragma unroll
        for (int m = 0; m < 4; ++m)
#pragma unroll
            for (int nt = 0; nt < 4; ++nt)
                acc[m][nt] = __builtin_amdgcn_mfma_f32_16x16x32_f16(aF[m], bF[nt][1], acc[m][nt], 0, 0, 0);
        __builtin_amdgcn_s_setprio(0);
        __builtin_amdgcn_s_barrier();

#pragma unroll
        for (int m = 0; m < 4; ++m)
            aF2[m] = *(const half8*)&smem[abase + aoff + (m + 4) * 1024 + (sl0 ^ 32)];
        if (t + 2 < NTB) {
            STAGE_B(t + 2, 1);
            asm volatile("s_waitcnt vmcnt(4)" ::: "memory");
        } else {
            asm volatile("s_waitcnt vmcnt(0)" ::: "memory");
        }
        __builtin_amdgcn_s_barrier();
        asm volatile("s_waitcnt lgkmcnt(0)" ::: "memory");
        __builtin_amdgcn_s_setprio(1);
#pragma unroll
        for (int m = 0; m < 4; ++m)
#pragma unroll
            for (int nt = 0; nt < 4; ++nt)
                acc[m + 4][nt] = __builtin_amdgcn_mfma_f32_16x16x32_f16(aF2[m], bF[nt][1], acc[m + 4][nt], 0, 0, 0);
        __builtin_amdgcn_s_setprio(0);
        __builtin_amdgcn_s_barrier();
    }

    uint16_t* ob = qk + (size_t)b * SS * SS;
#pragma unroll
    for (int mt = 0; mt < 8; ++mt) {
#pragma unroll
        for (int nt = 0; nt < 4; ++nt) {
            const int srow = s0 + wm * 128 + mt * 16 + quad * 4;
            const int tcol = t0 + wn * 64 + nt * 16 + fm;
#pragma unroll
            for (int reg = 0; reg < 4; ++reg)
                ob[(size_t)(srow + reg) * SS + tcol] = f2h(acc[mt][nt][reg]);
        }
    }
}

// ---------------------------------------------------------------- softmax
__global__ __launch_bounds__(256) void softmax_inplace(uint16_t* __restrict__ qk)
{
    const size_t row = blockIdx.x;
    uint16_t* x = qk + row * SS;
    const int tid  = threadIdx.x;
    const int lane = tid & 63;
    const int wave = tid >> 6;

    uintx4 raw = *(const uintx4*)(x + tid * 8);
    float v[8];
#pragma unroll
    for (int i = 0; i < 4; ++i) {
        uint32_t u = raw[i];
        v[2 * i]     = h2f(u & 0xffffu) * 0.125f;
        v[2 * i + 1] = h2f(u >> 16) * 0.125f;
    }
    float m = v[0];
#pragma unroll
    for (int j = 1; j < 8; ++j) m = fmaxf(m, v[j]);
#pragma unroll
    for (int off = 1; off < 64; off <<= 1) m = fmaxf(m, __shfl_xor(m, off, 64));
    __shared__ float red[8];
    if (lane == 0) red[wave] = m;
    __syncthreads();
    m = fmaxf(fmaxf(red[0], red[1]), fmaxf(red[2], red[3]));

    float s = 0.f;
#pragma unroll
    for (int j = 0; j < 8; ++j) { v[j] = __expf(v[j] - m); s += v[j]; }
#pragma unroll
    for (int off = 1; off < 64; off <<= 1) s += __shfl_xor(s, off, 64);
    if (lane == 0) red[4 + wave] = s;
    __syncthreads();
    s = (red[4] + red[5]) + (red[6] + red[7]);
    const float inv = 1.0f / s;
#pragma unroll
    for (int i = 0; i < 4; ++i)
        raw[i] = pk2h(v[2 * i] * inv, v[2 * i + 1] * inv);
    *(uintx4*)(x + tid * 8) = raw;
}

// ---------------------------------------------------------------- GEMM2a
// tmp[s][d] = sum_u attn[s][u] * qT[d][u]  (M=2048, N=512, K=2048), f16.
// 128x128 tile, 512 thr / 8 waves (2M x 4N), per-wave 64x32 output.
// 2-phase counted-vmcnt pipeline, distance-2 prefetch both operands.
// Full tile = 1024 x 16B chunks; each thread stages 2 chunks per operand
// (tid and tid+512) -> 4 gload_lds per tile; vmcnt(4) steady state.
//   P1: ds_read all 12 frags of tile t ; lgkm0 ; MFMA ks0 ; bar1
//   P2: STAGE A(t+2),B(t+2) (same buf as t, safe after bar1) ; vmcnt(4)
//       (t+1 landed) ; bar2 ; MFMA ks1
// Accumulation order (t asc, ks0 then ks1) identical to round-5 gemm2a.
__global__ __launch_bounds__(512, 2) void gemm2a_kernel(
    const uint16_t* __restrict__ attn, const uint16_t* __restrict__ qT,
    uint16_t* __restrict__ tmp)
{
    const int b  = blockIdx.z;
    const int s0 = blockIdx.y * 128;
    const int t0 = blockIdx.x * 128;   // d-dim tile, 0..511
    const uint16_t* ab = attn + (size_t)b * SS * SS;   // ld SS
    const uint16_t* bb = qT   + (size_t)b * DD * SS;   // ld SS

    // halfs: Abuf0 [0,8192) Abuf1 [8192,16384) Bbuf0 [16384,24576) Bbuf1 [24576,32768)
    __shared__ uint16_t smem[32768];   // 64 KiB

    const int tid  = threadIdx.x;
    const int lane = tid & 63;
    const int wave = tid >> 6;
    const int wm   = wave >> 2;   // 0..1 (M half: 64 rows)
    const int wn   = wave & 3;    // 0..3 (N quarter: 32 cols)
    const int fm   = lane & 15;
    const int quad = lane >> 4;

    floatx4 acc[4][2];
#pragma unroll
    for (int i = 0; i < 4; ++i)
#pragma unroll
        for (int j = 0; j < 2; ++j)
            acc[i][j] = (floatx4)0.0f;

    // swizzled read addressing: tile [128 rows][8 slots of 8 halfs]
    // logical slot = ks*4+quad ; phys = logical ^ (row&7) ; row&7 == fm&7
    const int sl0  = (quad ^ (fm & 7)) * 8;           // ks0 ; ks1 -> sl0^32
    const int aoff = (wm * 64 + fm) * 64;             // + mt*1024 + slot
    const int boff = 16384 + (wn * 32 + fm) * 64;     // + nt*1024 + slot

    // staging: tile = 1024 chunks of 16B; thread stages chunks tid and tid+512.
    // chunk c -> row c>>3 ; phys slot c&7 holds logical (c&7)^(row&7)
    // (inverse-swizzled global source keeps LDS dest linear).
    const int r0 = tid >> 3;                           // rows 0..63
    const int l0 = (((tid & 7) ^ (r0 & 7))) * 8;
    const int r1 = r0 + 64;                            // rows 64..127
    const int l1 = (((tid & 7) ^ (r1 & 7))) * 8;       // == l0 (r1&7==r0&7)
    const int ldsW = wave * 512;   // wave-uniform LDS dest (halfs), 64 lanes x 8

    auto STAGE_A = [&](int tt) {
        uint16_t* base = &smem[(tt & 1) * 8192 + ldsW];
        __builtin_amdgcn_global_load_lds(
            (GLOBAL_AS void*)(ab + (size_t)(s0 + r0) * SS + tt * 64 + l0),
            (LDS_AS void*)(base), 16, 0, 0);
        __builtin_amdgcn_global_load_lds(
            (GLOBAL_AS void*)(ab + (size_t)(s0 + r1) * SS + tt * 64 + l1),
            (LDS_AS void*)(base + 4096), 16, 0, 0);
    };
    auto STAGE_B = [&](int tt) {
        uint16_t* base = &smem[16384 + (tt & 1) * 8192 + ldsW];
        __builtin_amdgcn_global_load_lds(
            (GLOBAL_AS void*)(bb + (size_t)(t0 + r0) * SS + tt * 64 + l0),
            (LDS_AS void*)(base), 16, 0, 0);
        __builtin_amdgcn_global_load_lds(
            (GLOBAL_AS void*)(bb + (size_t)(t0 + r1) * SS + tt * 64 + l1),
            (LDS_AS void*)(base + 4096), 16, 0, 0);
    };

    // prologue: tiles 0,1 in flight (8 loads); wait tile 0 (leave tile 1's 4)
    STAGE_A(0); STAGE_B(0); STAGE_A(1); STAGE_B(1);
    asm volatile("s_waitcnt vmcnt(4)" ::: "memory");
    __builtin_amdgcn_s_barrier();

    half8 aF[4][2], bF[2][2];

    for (int t = 0; t < NT2A; ++t) {
        const int buf = (t & 1) * 8192;

        // ===== P1: read all 12 frags of tile t ; MFMA ks0
#pragma unroll
        for (int m = 0; m < 4; ++m) {
            aF[m][0] = *(const half8*)&smem[buf + aoff + m * 1024 + sl0];
            aF[m][1] = *(const half8*)&smem[buf + aoff + m * 1024 + (sl0 ^ 32)];
        }
#pragma unroll
        for (int n = 0; n < 2; ++n) {
            bF[n][0] = *(const half8*)&smem[buf + boff + n * 1024 + sl0];
            bF[n][1] = *(const half8*)&smem[buf + boff + n * 1024 + (sl0 ^ 32)];
        }
        asm volatile("s_waitcnt lgkmcnt(0)" ::: "memory");
        __builtin_amdgcn_s_setprio(1);
#pragma unroll
        for (int m = 0; m < 4; ++m)
#pragma unroll
            for (int n = 0; n < 2; ++n)
                acc[m][n] = __builtin_amdgcn_mfma_f32_16x16x32_f16(aF[m][0], bF[n][0], acc[m][n], 0, 0, 0);
        __builtin_amdgcn_s_setprio(0);
        __builtin_amdgcn_s_barrier();   // bar1: all waves done reading tile t

        // ===== P2: stage t+2 (same buffer as t; safe after bar1) ; MFMA ks1
        if (t + 2 < NT2A) {
            STAGE_A(t + 2); STAGE_B(t + 2);
            asm volatile("s_waitcnt vmcnt(4)" ::: "memory");   // t+1 landed
        } else {
            asm volatile("s_waitcnt vmcnt(0)" ::: "memory");
        }
        __builtin_amdgcn_s_barrier();   // bar2: t+1 resident for every wave
        __builtin_amdgcn_s_setprio(1);
#pragma unroll
        for (int m = 0; m < 4; ++m)
#pragma unroll
            for (int n = 0; n < 2; ++n)
                acc[m][n] = __builtin_amdgcn_mfma_f32_16x16x32_f16(aF[m][1], bF[n][1], acc[m][n], 0, 0, 0);
        __builtin_amdgcn_s_setprio(0);
    }

    uint16_t* tb = tmp + (size_t)b * SS * DD;
#pragma unroll
    for (int mt = 0; mt < 4; ++mt) {
#pragma unroll
        for (int n = 0; n < 2; ++n) {
            const int srw  = s0 + wm * 64 + mt * 16 + quad * 4;
            const int tcol = t0 + wn * 32 + n * 16 + fm;
#pragma unroll
            for (int reg = 0; reg < 4; ++reg)
                tb[(size_t)(srw + reg) * DD + tcol] = f2h(acc[mt][n][reg]);
        }
    }
}

// ---------------------------------------------------------------- GEMM2b
// out[s][t] = sum_d tmp[s][d] * kH[t][d]  (f16, 256^2 8-phase, f32 out)
__global__ __launch_bounds__(512, 2) void gemm2b_kernel(
    const uint16_t* __restrict__ tmp, const uint16_t* __restrict__ kH,
    float* __restrict__ out)
{
    const int b  = blockIdx.z;
    const int s0 = blockIdx.y * 256;
    const int t0 = blockIdx.x * 256;
    const uint16_t* ab = tmp + (size_t)b * SS * DD;
    const uint16_t* bb = kH  + (size_t)b * SS * DD;

    __shared__ uint16_t smem[65536];

    const int tid  = threadIdx.x;
    const int lane = tid & 63;
    const int wave = tid >> 6;
    const int wm   = wave >> 2;
    const int wn   = wave & 3;
    const int fm   = lane & 15;
    const int quad = lane >> 4;

    floatx4 acc[8][4];
#pragma unroll
    for (int i = 0; i < 8; ++i)
#pragma unroll
        for (int j = 0; j < 4; ++j)
            acc[i][j] = (floatx4)0.0f;

    const int sl0  = (quad ^ (fm & 7)) * 8;
    const int aoff = (wm * 128 + fm) * 64;
    const int boff = 32768 + (wn * 64 + fm) * 64;

    const int c0 = wave * 128 + lane;
    const int r0 = c0 >> 3;  const int l0 = ((c0 & 7) ^ (r0 & 7)) * 8;
    const int c1 = c0 + 64;
    const int r1 = c1 >> 3;  const int l1 = ((c1 & 7) ^ (r1 & 7)) * 8;
    const int ldsW = wave * 1024;

    auto STAGE_A = [&](int tt, int h) {
        uint16_t* base = &smem[(tt & 1) * 16384 + h * 8192 + ldsW];
        __builtin_amdgcn_global_load_lds(
            (GLOBAL_AS void*)(ab + (size_t)(s0 + h * 128 + r0) * DD + tt * 64 + l0),
            (LDS_AS void*)(base), 16, 0, 0);
        __builtin_amdgcn_global_load_lds(
            (GLOBAL_AS void*)(ab + (size_t)(s0 + h * 128 + r1) * DD + tt * 64 + l1),
            (LDS_AS void*)(base + 512), 16, 0, 0);
    };
    auto STAGE_B = [&](int tt, int h) {
        uint16_t* base = &smem[32768 + (tt & 1) * 16384 + h * 8192 + ldsW];
        __builtin_amdgcn_global_load_lds(
            (GLOBAL_AS void*)(bb + (size_t)(t0 + h * 128 + r0) * DD + tt * 64 + l0),
            (LDS_AS void*)(base), 16, 0, 0);
        __builtin_amdgcn_global_load_lds(
            (GLOBAL_AS void*)(bb + (size_t)(t0 + h * 128 + r1) * DD + tt * 64 + l1),
            (LDS_AS void*)(base + 512), 16, 0, 0);
    };

    STAGE_A(0, 0); STAGE_A(0, 1); STAGE_B(0, 0); STAGE_B(0, 1);
    STAGE_B(1, 0); STAGE_B(1, 1);
    asm volatile("s_waitcnt vmcnt(4)" ::: "memory");
    __builtin_amdgcn_s_barrier();

    half8 aF[4], aF2[4], bF[4][2];

    for (int t = 0; t < NTB; ++t) {
        const int abase = (t & 1) * 16384;
        const int bbase = (t & 1) * 16384;

#pragma unroll
        for (int nt = 0; nt < 4; ++nt) {
            bF[nt][0] = *(const half8*)&smem[bbase + boff + nt * 1024 + sl0];
            bF[nt][1] = *(const half8*)&smem[bbase + boff + nt * 1024 + (sl0 ^ 32)];
        }
#pragma unroll
        for (int m = 0; m < 4; ++m)
            aF[m] = *(const half8*)&smem[abase + aoff + m * 1024 + sl0];
        if (t + 1 < NTB) STAGE_A(t + 1, 0);
        __builtin_amdgcn_s_barrier();
        asm volatile("s_waitcnt lgkmcnt(0)" ::: "memory");
        __builtin_amdgcn_s_setprio(1);
#pragma unroll
        for (int m = 0; m < 4; ++m)
#pragma unroll
            for (int nt = 0; nt < 4; ++nt)
                acc[m][nt] = __builtin_amdgcn_mfma_f32_16x16x32_f16(aF[m], bF[nt][0], acc[m][nt], 0, 0, 0);
        __builtin_amdgcn_s_setprio(0);
        __builtin_amdgcn_s_barrier();

#pragma unroll
        for (int m = 0; m < 4; ++m)
            aF2[m] = *(const half8*)&smem[abase + aoff + (m + 4) * 1024 + sl0];
        if (t + 1 < NTB) STAGE_A(t + 1, 1);
        __builtin_amdgcn_s_barrier();
        asm volatile("s_waitcnt lgkmcnt(0)" ::: "memory");
        __builtin_amdgcn_s_setprio(1);
#pragma unroll
        for (int m = 0; m < 4; ++m)
#pragma unroll
            for (int nt = 0; nt < 4; ++nt)
                acc[m + 4][nt] = __builtin_amdgcn_mfma_f32_16x16x32_f16(aF2[m], bF[nt][0], acc[m + 4][nt], 0, 0, 0);
        __builtin_amdgcn_s_setprio(0);
        __builtin_amdgcn_s_barrier();

#pragma unroll
        for (int m = 0; m < 4; ++m)
            aF[m] = *(const half8*)&smem[abase + aoff + m * 1024 + (sl0 ^ 32)];
        if (t + 2 < NTB) STAGE_B(t + 2, 0);
        __builtin_amdgcn_s_barrier();
        asm volatile("s_waitcnt lgkmcnt(0)" ::: "memory");
        __builtin_amdgcn_s_setprio(1);
#pragma unroll
        for (int m = 0; m < 4; ++m)
#pragma unroll
            for (int nt = 0; nt < 4; ++nt)
                acc[m][nt] = __builtin_amdgcn_mfma_f32_16x16x32_f16(aF[m], bF[nt][1], acc[m][nt], 0, 0, 0);
        __builtin_amdgcn_s_setprio(0);
        __builtin_amdgcn_s_barrier();

#pragma unroll
        for (int m = 0; m < 4; ++m)
            aF2[m] = *(const half8*)&smem[abase + aoff + (m + 4) * 1024 + (sl0 ^ 32)];
        if (t + 2 < NTB) {
            STAGE_B(t + 2, 1);
            asm volatile("s_waitcnt vmcnt(4)" ::: "memory");
        } else {
            asm volatile("s_waitcnt vmcnt(0)" ::: "memory");
        }
        __builtin_amdgcn_s_barrier();
        asm volatile("s_waitcnt lgkmcnt(0)" ::: "memory");
        __builtin_amdgcn_s_setprio(1);
#pragma unroll
        for (int m = 0; m < 4; ++m)
#pragma unroll
            for (int nt = 0; nt < 4; ++nt)
                acc[m + 4][nt] = __builtin_amdgcn_mfma_f32_16x16x32_f16(aF2[m], bF[nt][1], acc[m + 4][nt], 0, 0, 0);
        __builtin_amdgcn_s_setprio(0);
        __builtin_amdgcn_s_barrier();
    }

    float* ob = out + (size_t)b * SS * SS;
#pragma unroll
    for (int mt = 0; mt < 8; ++mt) {
#pragma unroll
        for (int nt = 0; nt < 4; ++nt) {
            const int srow = s0 + wm * 128 + mt * 16 + quad * 4;
            const int tcol = t0 + wn * 64 + nt * 16 + fm;
#pragma unroll
            for (int reg = 0; reg < 4; ++reg)
                ob[(size_t)(srow + reg) * SS + tcol] = acc[mt][nt][reg];
        }
    }
}

extern "C" void kernel_launch(void* const* d_in, const int* in_sizes, int n_in,
                              void* d_out, int out_size, void* d_ws, size_t ws_size,
                              hipStream_t stream) {
    const float* q = (const float*)d_in[0];
    const float* k = (const float*)d_in[1];
    float* out = (float*)d_out;

    uint16_t* qk  = (uint16_t*)d_ws;                   // 4*2048*2048
    uint16_t* qT  = qk + (size_t)BATCH * SS * SS;      // 4*512*2048
    uint16_t* qH  = qT + (size_t)BATCH * DD * SS;      // 4*2048*512
    uint16_t* kH  = qH + (size_t)BATCH * SS * DD;      // 4*2048*512
    uint16_t* tmp = kH + (size_t)BATCH * SS * DD;      // 4*2048*512

    prep_kernel<<<dim3(32, 10, BATCH), 256, 0, stream>>>(q, k, qT, qH, kH);
    gemm1_kernel<<<dim3(SS / 256, SS / 256, BATCH), 512, 0, stream>>>(qH, kH, qk);
    softmax_inplace<<<dim3(BATCH * SS), 256, 0, stream>>>(qk);
    gemm2a_kernel<<<dim3(DD / 128, SS / 128, BATCH), 512, 0, stream>>>(qk, qT, tmp);
    gemm2b_kernel<<<dim3(SS / 256, SS / 256, BATCH), 512, 0, stream>>>(tmp, kH, out);
}